// Round 14
// baseline (2115.162 us; speedup 1.0000x reference)
//
#include <hip/hip_runtime.h>
#include <hip/hip_fp16.h>

#define HD 128
#define TLEN 49152
#define NBATCH 4
#define NCLS2 256
#define OWLEN 16386
#define SKIP0 (TLEN - OWLEN)
#define NLAY 28
#define NT 64          // time rows per tile
#define TPB 6          // tiles per block -> grid.x = 128
#define NTHR 512       // 8 waves, each owns 16 output channels
#define L0THR 256      // layer0 stays 4-wave
#define HNT 128        // head tile
#define HTHR 512

typedef _Float16 f16;
typedef _Float16 f16x8 __attribute__((ext_vector_type(8)));
typedef _Float16 f16x4 __attribute__((ext_vector_type(4)));
typedef float f32x4 __attribute__((ext_vector_type(4)));
typedef float f32x4u __attribute__((ext_vector_type(4), aligned(4)));

#define MFMA16(a, b, c) __builtin_amdgcn_mfma_f32_16x16x32_f16(a, b, c, 0, 0, 0)

// Counted-wait barriers: __syncthreads() forces vmcnt(0) drain (kills async
// staging). LDS-only phases need only lgkmcnt(0); vmcnt drained once per tile.
__device__ __forceinline__ void bar_lgkm() {
    asm volatile("s_waitcnt lgkmcnt(0)" ::: "memory");
    __builtin_amdgcn_s_barrier();
    __builtin_amdgcn_sched_barrier(0);
}
__device__ __forceinline__ void bar_full() {
    asm volatile("s_waitcnt vmcnt(0) lgkmcnt(0)" ::: "memory");
    __builtin_amdgcn_s_barrier();
    __builtin_amdgcn_sched_barrier(0);
}

__device__ __forceinline__ float fast_tanh(float x) {
    float e = __expf(-2.f * fabsf(x));
    float t = (1.f - e) * __builtin_amdgcn_rcpf(1.f + e);
    return copysignf(t, x);
}
__device__ __forceinline__ float fast_sig(float x) {
    return __builtin_amdgcn_rcpf(1.f + __expf(-x));
}

// swizzled LDS byte offset for a [rows][128ch] f16 tile (row stride 256B)
__device__ __forceinline__ int swzb(int row, int cb) { return row * 256 + (cb ^ ((row & 7) << 4)); }

// async global->LDS, 16B/lane. LDS dest linear; swizzle via pre-swizzled per-lane
// GLOBAL source address.
__device__ __forceinline__ void gld_lds16(const void* g, void* l) {
    __builtin_amdgcn_global_load_lds((const __attribute__((address_space(1))) void*)g,
                                     (__attribute__((address_space(3))) void*)l, 16, 0, 0);
}

// wave w stages rows [w*8, w*8+8) of a 64x128 f16 tile (two 1KB issues)
__device__ __forceinline__ void stage_async(const f16* __restrict__ rb, int tbase,
                                            char* buf, int w, int lane)
{
    int rgrp = lane >> 4;
    int cb = (lane & 15) * 16;
    #pragma unroll
    for (int q = 0; q < 2; ++q) {
        int row0 = w * 8 + q * 4;
        int r = row0 + rgrp;
        int gt = tbase + r;
        const char* src = (const char*)(rb + (size_t)gt * HD) + (cb ^ ((r & 7) << 4));
        gld_lds16(src, buf + row0 * 256);
    }
}

template <int NTH>
__device__ __forceinline__ void stage_f16n(const f16* __restrict__ src, int tbase, int tlim,
                                           char* dst, int nrows)
{
    int tid = threadIdx.x;
    int cg = tid & 15;
    for (int row = tid >> 4; row < nrows; row += NTH / 16) {
        int gt = tbase + row;
        f16x8 v;
        if (gt >= 0 && gt < tlim) {
            v = *(const f16x8*)(src + (size_t)gt * HD + cg * 8);
        } else {
            #pragma unroll
            for (int i = 0; i < 8; ++i) v[i] = (f16)0.f;
        }
        *(f16x8*)(dst + swzb(row, cg * 16)) = v;
    }
}

template <int NTH>
__device__ __forceinline__ void stage_f32n(const float* __restrict__ src, int tbase, int tlim,
                                           char* dst, int nrows)
{
    int tid = threadIdx.x;
    int cg = tid & 15;
    for (int row = tid >> 4; row < nrows; row += NTH / 16) {
        int gt = tbase + row;
        f16x8 v;
        if (gt >= 0 && gt < tlim) {
            const float* p = src + (size_t)gt * HD + cg * 8;
            f32x4 a = *(const f32x4*)p;
            f32x4 b = *(const f32x4*)(p + 4);
            #pragma unroll
            for (int i = 0; i < 4; ++i) v[i] = (f16)a[i];
            #pragma unroll
            for (int i = 0; i < 4; ++i) v[4 + i] = (f16)b[i];
        } else {
            #pragma unroll
            for (int i = 0; i < 8; ++i) v[i] = (f16)0.f;
        }
        *(f16x8*)(dst + swzb(row, cg * 16)) = v;
    }
}

// dense row-major output pass; rvbuf holds rv16; xnlds holds RAW residual input
// (affine sc/sh applied here from ss). ro/sb per-batch bases, rows by gt.
template <int FIRST, int NTH>
__device__ __forceinline__ void dense_out(const char* rvbuf, const char* xnlds,
                                          const float* __restrict__ xraw,
                                          const float* ss,
                                          f16* __restrict__ ro, float* __restrict__ sb,
                                          int t0, float* s1, float* s2, int wout)
{
    int tid = threadIdx.x;
    int cg = tid & 15;
    float scr[8], shr[8];
    if (!FIRST) {
        #pragma unroll
        for (int i = 0; i < 8; ++i) { scr[i] = ss[cg * 8 + i]; shr[i] = ss[128 + cg * 8 + i]; }
    }
    #pragma unroll
    for (int p = 0; p < NT / (NTH / 16); ++p) {
        int row = (tid >> 4) + p * (NTH / 16);
        int gt = t0 + row;
        f16x8 rv = *(const f16x8*)(rvbuf + swzb(row, cg * 16));
        if (wout) *(f16x8*)(ro + (size_t)gt * HD + cg * 8) = rv;
        float rvf[8];
        #pragma unroll
        for (int i = 0; i < 8; ++i) {
            rvf[i] = (float)rv[i];
            s1[i] += rvf[i];
            s2[i] += rvf[i] * rvf[i];
        }
        if (gt >= SKIP0) {
            float* sp = sb + (size_t)(gt - SKIP0) * HD + cg * 8;
            float xnf[8];
            if (FIRST) {
                float xv = xraw[gt];
                #pragma unroll
                for (int i = 0; i < 8; ++i) xnf[i] = xv;
            } else {
                f16x8 xn = *(const f16x8*)(xnlds + swzb(row, cg * 16));
                #pragma unroll
                for (int i = 0; i < 8; ++i) xnf[i] = (float)xn[i] * scr[i] + shr[i];
            }
            f32x4 a, b2;
            if (FIRST) {
                #pragma unroll
                for (int i = 0; i < 4; ++i) { a[i] = rvf[i] - xnf[i]; b2[i] = rvf[4 + i] - xnf[4 + i]; }
            } else {
                a = *(const f32x4*)sp;
                b2 = *(const f32x4*)(sp + 4);
                #pragma unroll
                for (int i = 0; i < 4; ++i) { a[i] += rvf[i] - xnf[i]; b2[i] += rvf[4 + i] - xnf[4 + i]; }
            }
            *(f32x4*)sp = a;
            *(f32x4*)(sp + 4) = b2;
        }
    }
}

// cross-wave stats flush; NW = waves per block
template <int NW>
__device__ __forceinline__ void flush_statsN(float* s1, float* s2,
                                             float (*slds)[2][HD], float* __restrict__ gs)
{
    int tid = threadIdx.x;
    int lane = tid & 63, w = tid >> 6;
    #pragma unroll
    for (int i = 0; i < 8; ++i) {
        s1[i] += __shfl_xor(s1[i], 16); s1[i] += __shfl_xor(s1[i], 32);
        s2[i] += __shfl_xor(s2[i], 16); s2[i] += __shfl_xor(s2[i], 32);
    }
    if (lane < 16) {
        #pragma unroll
        for (int i = 0; i < 8; ++i) {
            slds[w][0][lane * 8 + i] = s1[i];
            slds[w][1][lane * 8 + i] = s2[i];
        }
    }
    __syncthreads();
    if (tid < HD) {
        float a = 0.f;
        #pragma unroll
        for (int k = 0; k < NW; ++k) a += slds[k][0][tid];
        atomicAdd(&gs[tid], a);
    } else if (tid < 2 * HD) {
        int c = tid - HD;
        float a = 0.f;
        #pragma unroll
        for (int k = 0; k < NW; ++k) a += slds[k][1][c];
        atomicAdd(&gs[HD + c], a);
    }
}

// Software-pipelined + counted-wait barriers: vmcnt drained ONCE per tile (B0);
// B1-B3 are lgkmcnt-only so the t+1 stage loads stay in flight across them.
__global__ __launch_bounds__(NTHR, 2)
void layer_kernel(const f16* __restrict__ rin, f16* __restrict__ rout,
                  float* __restrict__ ssum, float* __restrict__ gstats,
                  const f16* __restrict__ wf, const f16* __restrict__ wg,
                  const f16* __restrict__ w1,
                  const float* __restrict__ bf, const float* __restrict__ bg,
                  const float* __restrict__ b1,
                  const float* __restrict__ gamma, const float* __restrict__ beta,
                  int layer, int dil, int last)
{
    __shared__ __align__(16) char bufs[2][2][NT * 256];  // [parity][tap] 64 KB
    __shared__ float ss[256];
    __shared__ float sbias[3][HD];
    __shared__ float slds[8][2][HD];

    int tid = threadIdx.x;
    int b = blockIdx.y;

    if (tid < HD) {
        float n = (float)(NBATCH * TLEN);
        float s = gstats[(layer - 1) * 256 + tid];
        float q = gstats[(layer - 1) * 256 + 128 + tid];
        float mean = s / n;
        float var = q / n - mean * mean;
        float sc = gamma[tid] * rsqrtf(var + 1e-5f);
        ss[tid] = sc;
        ss[128 + tid] = beta[tid] - mean * sc;
        sbias[0][tid] = bf[tid];
        sbias[1][tid] = bg[tid];
        sbias[2][tid] = b1[tid];
    }
    __syncthreads();   // ss ready for weight fold

    int lane = tid & 63, w = tid >> 6;
    int m0 = w * 16;
    int lrow = lane & 15, lgrp = lane >> 4;
    const f32x4 fz = {0.f, 0.f, 0.f, 0.f};

    // load conv weights, fold BN scale into them, accumulate shift->bias corr
    f16x8 wfr[2][4], wgr[2][4], w1r[4];
    float corrF = 0.f, corrG = 0.f;
    #pragma unroll
    for (int kk = 0; kk < 4; ++kk) {
        int ck = kk * 32 + lgrp * 8;
        float scv[8], shv[8];
        #pragma unroll
        for (int i = 0; i < 8; ++i) { scv[i] = ss[ck + i]; shv[i] = ss[128 + ck + i]; }
        #pragma unroll
        for (int tap = 0; tap < 2; ++tap) {
            int o = (m0 + lrow) * HD + ck;
            f16x8 vF = *(const f16x8*)(wf + tap * HD * HD + o);
            f16x8 vG = *(const f16x8*)(wg + tap * HD * HD + o);
            #pragma unroll
            for (int i = 0; i < 8; ++i) {
                corrF += (float)vF[i] * shv[i];
                corrG += (float)vG[i] * shv[i];
                vF[i] = (f16)((float)vF[i] * scv[i]);
                vG[i] = (f16)((float)vG[i] * scv[i]);
            }
            wfr[tap][kk] = vF;
            wgr[tap][kk] = vG;
        }
        w1r[kk] = *(const f16x8*)(w1 + (m0 + lrow) * HD + ck);
    }
    corrF += __shfl_xor(corrF, 16); corrF += __shfl_xor(corrF, 32);
    corrG += __shfl_xor(corrG, 16); corrG += __shfl_xor(corrG, 32);
    if (lane < 16) {
        sbias[0][m0 + lane] += corrF;
        sbias[1][m0 + lane] += corrG;
    }

    const f16* rb = rin + (size_t)b * TLEN * HD;
    f16* ro = rout + (size_t)b * TLEN * HD;
    float* sb = ssum + (size_t)b * OWLEN * HD;

    float s1[8] = {}, s2[8] = {};
    int tb = blockIdx.x * TPB * NT;
    int c0 = m0 + lgrp * 4;
    int cg = tid & 15;

    // prologue: issue tile-0 stage (raw)
    stage_async(rb, tb, bufs[0][1], w, lane);
    stage_async(rb, tb - dil, bufs[0][0], w, lane);

    for (int ti = 0; ti < TPB; ++ti) {
        int t0 = tb + ti * NT;
        int cur = ti & 1;
        int prv = cur ^ 1;
        bar_full();   // B0: staged tiles landed + rv writes(ti-1) visible

        // causal boundary patch: padded positions = -sh/sc raw so normalized = 0
        if (t0 < dil) {
            for (int r0 = tid >> 4; r0 < NT; r0 += NTHR / 16) {
                if (t0 - dil + r0 < 0) {
                    f16x8 v;
                    #pragma unroll
                    for (int i = 0; i < 8; ++i)
                        v[i] = (f16)(-ss[128 + cg * 8 + i] / ss[cg * 8 + i]);
                    *(f16x8*)(bufs[cur][0] + swzb(r0, cg * 16)) = v;
                }
            }
            bar_lgkm();
        }

        // R1: dense_out(t-1) [parity prv] ∥ fg GEMM(t) [parity cur]
        if (ti > 0)
            dense_out<0, NTHR>(bufs[prv][0], bufs[prv][1], nullptr, ss,
                               ro, sb, t0 - NT, s1, s2, !last);

        f32x4 facc[4], gacc[4];
        #pragma unroll
        for (int ni = 0; ni < 4; ++ni) { facc[ni] = fz; gacc[ni] = fz; }
        __builtin_amdgcn_s_setprio(1);
        #pragma unroll
        for (int tap = 0; tap < 2; ++tap) {
            const char* xt = bufs[cur][tap];
            #pragma unroll
            for (int kk = 0; kk < 4; ++kk) {
                f16x8 bx[4];
                #pragma unroll
                for (int ni = 0; ni < 4; ++ni)
                    bx[ni] = *(const f16x8*)(xt + swzb(ni * 16 + lrow, (kk * 32 + lgrp * 8) * 2));
                #pragma unroll
                for (int ni = 0; ni < 4; ++ni) {
                    facc[ni] = MFMA16(wfr[tap][kk], bx[ni], facc[ni]);
                    gacc[ni] = MFMA16(wgr[tap][kk], bx[ni], gacc[ni]);
                }
            }
        }
        __builtin_amdgcn_s_setprio(0);
        bar_lgkm();   // B1: tap reads + dense's prv LDS reads done

        // R2: issue stage(t+1) into prv parity; gate-write h into bufs[cur][0]
        if (ti + 1 < TPB) {
            stage_async(rb, t0 + NT, bufs[prv][1], w, lane);
            stage_async(rb, t0 + NT - dil, bufs[prv][0], w, lane);
        }
        {
            float bfv[4], bgv[4];
            #pragma unroll
            for (int r = 0; r < 4; ++r) { bfv[r] = sbias[0][c0 + r]; bgv[r] = sbias[1][c0 + r]; }
            #pragma unroll
            for (int ni = 0; ni < 4; ++ni) {
                int t = ni * 16 + lrow;
                f16x4 hv;
                #pragma unroll
                for (int r = 0; r < 4; ++r) {
                    float fv = facc[ni][r] + bfv[r];
                    float gv = gacc[ni][r] + bgv[r];
                    hv[r] = (f16)(fast_tanh(fv) * fast_sig(gv));
                }
                *(f16x4*)(bufs[cur][0] + swzb(t, c0 * 2)) = hv;
            }
        }
        bar_lgkm();   // B2: h writes visible; stage loads remain in flight

        // R3: W1 GEMM, weights from registers
        f32x4 sacc[4];
        #pragma unroll
        for (int ni = 0; ni < 4; ++ni) sacc[ni] = fz;
        __builtin_amdgcn_s_setprio(1);
        #pragma unroll
        for (int kk = 0; kk < 4; ++kk) {
            int cb = (kk * 32 + lgrp * 8) * 2;
            f16x8 bx[4];
            #pragma unroll
            for (int ni = 0; ni < 4; ++ni)
                bx[ni] = *(const f16x8*)(bufs[cur][0] + swzb(ni * 16 + lrow, cb));
            #pragma unroll
            for (int ni = 0; ni < 4; ++ni)
                sacc[ni] = MFMA16(w1r[kk], bx[ni], sacc[ni]);
        }
        __builtin_amdgcn_s_setprio(0);
        bar_lgkm();   // B3: h reads done

        // R4: rv16 = sacc + b1 + affine(raw x) into bufs[cur][0]
        {
            float bb[4], sc0[4], sh0[4];
            #pragma unroll
            for (int r = 0; r < 4; ++r) {
                bb[r] = sbias[2][c0 + r];
                sc0[r] = ss[c0 + r];
                sh0[r] = ss[128 + c0 + r];
            }
            #pragma unroll
            for (int ni = 0; ni < 4; ++ni) {
                int tl = ni * 16 + lrow;
                f16x4 xv = *(const f16x4*)(bufs[cur][1] + swzb(tl, c0 * 2));  // RAW
                f16x4 rv16;
                #pragma unroll
                for (int r = 0; r < 4; ++r)
                    rv16[r] = (f16)(sacc[ni][r] + bb[r] + ((float)xv[r] * sc0[r] + sh0[r]));
                *(f16x4*)(bufs[cur][0] + swzb(tl, c0 * 2)) = rv16;
            }
        }
        // loop -> B0
    }

    bar_lgkm();
    dense_out<0, NTHR>(bufs[(TPB - 1) & 1][0], bufs[(TPB - 1) & 1][1], nullptr, ss,
                       ro, sb, tb + (TPB - 1) * NT, s1, s2, !last);

    if (!last) flush_statsN<8>(s1, s2, slds, gstats + layer * 256);
}

__global__ __launch_bounds__(L0THR, 4)
void layer0_kernel(const float* __restrict__ x,
                   const float* __restrict__ Wf0, const float* __restrict__ bf0,
                   const float* __restrict__ Wg0, const float* __restrict__ bg0,
                   const f16* __restrict__ w10, const float* __restrict__ b10,
                   f16* __restrict__ rout, float* __restrict__ ssum,
                   float* __restrict__ gstats)
{
    __shared__ __align__(16) char hbuf[NT * 256];
    __shared__ __align__(16) char w1s[32768];
    __shared__ float wl[6][HD];
    __shared__ float slds0[4][2][HD];
    int tid = threadIdx.x;
    int b = blockIdx.y;
    if (tid < HD) {
        wl[0][tid] = Wf0[tid * 2 + 0]; wl[1][tid] = Wf0[tid * 2 + 1]; wl[2][tid] = bf0[tid];
        wl[3][tid] = Wg0[tid * 2 + 0]; wl[4][tid] = Wg0[tid * 2 + 1]; wl[5][tid] = bg0[tid];
    }
    {
        int cg = tid & 15;
        #pragma unroll
        for (int p = 0; p < 8; ++p) {
            int row = (tid >> 4) + p * 16;
            f16x8 v = *(const f16x8*)(w10 + row * HD + cg * 8);
            *(f16x8*)(w1s + swzb(row, cg * 16)) = v;
        }
    }
    __syncthreads();
    const float* xb = x + (size_t)b * TLEN;
    f16* ro = rout + (size_t)b * TLEN * HD;
    float* sb = ssum + (size_t)b * OWLEN * HD;
    int cg = tid & 15;
    int lane = tid & 63, w = tid >> 6;
    int m0 = w * 32;
    int lrow = lane & 15, lgrp = lane >> 4;
    const f32x4 fz = {0.f, 0.f, 0.f, 0.f};
    float s1[8] = {}, s2[8] = {};

    for (int ti = 0; ti < TPB; ++ti) {
        int t0 = (blockIdx.x * TPB + ti) * NT;
        if (ti) __syncthreads();
        #pragma unroll
        for (int p = 0; p < NT / 16; ++p) {
            int row = (tid >> 4) + p * 16;
            int gt = t0 + row;
            float xc = xb[gt];
            float xm = (gt >= 1) ? xb[gt - 1] : 0.f;
            f16x8 hv;
            #pragma unroll
            for (int i = 0; i < 8; ++i) {
                int c = cg * 8 + i;
                float fv = wl[0][c] * xm + wl[1][c] * xc + wl[2][c];
                float gv = wl[3][c] * xm + wl[4][c] * xc + wl[5][c];
                hv[i] = (f16)(fast_tanh(fv) * fast_sig(gv));
            }
            *(f16x8*)(hbuf + swzb(row, cg * 16)) = hv;
        }
        __syncthreads();

        f32x4 sacc[2][4];
        #pragma unroll
        for (int mi = 0; mi < 2; ++mi)
            #pragma unroll
            for (int ni = 0; ni < 4; ++ni) sacc[mi][ni] = fz;
        #pragma unroll
        for (int kk = 0; kk < 4; ++kk) {
            int cb = (kk * 32 + lgrp * 8) * 2;
            f16x8 a[2], bx[4];
            #pragma unroll
            for (int mi = 0; mi < 2; ++mi)
                a[mi] = *(const f16x8*)(w1s + swzb(m0 + mi * 16 + lrow, cb));
            #pragma unroll
            for (int ni = 0; ni < 4; ++ni)
                bx[ni] = *(const f16x8*)(hbuf + swzb(ni * 16 + lrow, cb));
            #pragma unroll
            for (int mi = 0; mi < 2; ++mi)
                #pragma unroll
                for (int ni = 0; ni < 4; ++ni)
                    sacc[mi][ni] = MFMA16(a[mi], bx[ni], sacc[mi][ni]);
        }
        __syncthreads();

        #pragma unroll
        for (int mi = 0; mi < 2; ++mi) {
            int c0 = m0 + mi * 16 + lgrp * 4;
            float bb[4];
            #pragma unroll
            for (int r = 0; r < 4; ++r) bb[r] = b10[c0 + r];
            #pragma unroll
            for (int ni = 0; ni < 4; ++ni) {
                int tl = ni * 16 + lrow;
                float xn = xb[t0 + tl];
                f16x4 rv16;
                #pragma unroll
                for (int r = 0; r < 4; ++r)
                    rv16[r] = (f16)(sacc[mi][ni][r] + bb[r] + xn);
                *(f16x4*)(hbuf + swzb(tl, c0 * 2)) = rv16;
            }
        }
        __syncthreads();
        dense_out<1, L0THR>(hbuf, nullptr, xb, nullptr, ro, sb, t0, s1, s2, 1);
    }
    flush_statsN<4>(s1, s2, slds0, gstats);
}

template <int SRC16>
__global__ __launch_bounds__(HTHR)
void head_gemm(const void* __restrict__ in, const f16* __restrict__ wm,
               const float* __restrict__ bias, f16* __restrict__ out)
{
    __shared__ __align__(16) char xt[HNT * 256];
    int tid = threadIdx.x;
    int b = blockIdx.y;
    int t0 = blockIdx.x * HNT;
    if (SRC16)
        stage_f16n<HTHR>((const f16*)in + (size_t)b * OWLEN * HD, t0, OWLEN, xt, HNT);
    else
        stage_f32n<HTHR>((const float*)in + (size_t)b * OWLEN * HD, t0, OWLEN, xt, HNT);
    __syncthreads();
    int lane = tid & 63, w = tid >> 6;
    int m0 = (w >> 1) * 32, n0 = (w & 1) * 64;
    int lrow = lane & 15, lgrp = lane >> 4;
    const f32x4 fz = {0.f, 0.f, 0.f, 0.f};
    f32x4 acc[2][4];
    #pragma unroll
    for (int mi = 0; mi < 2; ++mi)
        #pragma unroll
        for (int ni = 0; ni < 4; ++ni) acc[mi][ni] = fz;
    #pragma unroll
    for (int kk = 0; kk < 4; ++kk) {
        int kr = kk * 32 + lgrp * 8;
        f16x8 a[2], bx[4];
        #pragma unroll
        for (int mi = 0; mi < 2; ++mi)
            a[mi] = *(const f16x8*)(wm + (m0 + mi * 16 + lrow) * HD + kr);
        #pragma unroll
        for (int ni = 0; ni < 4; ++ni)
            bx[ni] = *(const f16x8*)(xt + swzb(n0 + ni * 16 + lrow, kr * 2));
        #pragma unroll
        for (int mi = 0; mi < 2; ++mi)
            #pragma unroll
            for (int ni = 0; ni < 4; ++ni)
                acc[mi][ni] = MFMA16(a[mi], bx[ni], acc[mi][ni]);
    }
    __syncthreads();   // xt reads done; reuse for relu output
    #pragma unroll
    for (int mi = 0; mi < 2; ++mi) {
        int c0 = m0 + mi * 16 + lgrp * 4;
        float bv[4];
        #pragma unroll
        for (int r = 0; r < 4; ++r) bv[r] = bias[c0 + r];
        #pragma unroll
        for (int ni = 0; ni < 4; ++ni) {
            int tl = n0 + ni * 16 + lrow;
            f16x4 v;
            #pragma unroll
            for (int r = 0; r < 4; ++r) v[r] = (f16)fmaxf(acc[mi][ni][r] + bv[r], 0.f);
            *(f16x4*)(xt + swzb(tl, c0 * 2)) = v;
        }
    }
    __syncthreads();
    f16* ob = out + (size_t)b * OWLEN * HD;
    int cg = tid & 15;
    #pragma unroll
    for (int p = 0; p < HNT / 32; ++p) {
        int row = (tid >> 4) + p * 32;
        int gt = t0 + row;
        if (gt < OWLEN) {
            f16x8 v = *(const f16x8*)(xt + swzb(row, cg * 16));
            *(f16x8*)(ob + (size_t)gt * HD + cg * 8) = v;
        }
    }
}

__global__ __launch_bounds__(HTHR)
void final_kernel(const f16* __restrict__ y2, const f16* __restrict__ whc,
                  const float* __restrict__ bhc, float* __restrict__ out)
{
    __shared__ __align__(16) char yt[130 * 256];
    int tid = threadIdx.x;
    int b = blockIdx.y;
    int t0 = blockIdx.x * HNT;
    stage_f16n<HTHR>(y2 + (size_t)b * OWLEN * HD, t0, OWLEN, yt, 130);
    __syncthreads();
    int lane = tid & 63, w = tid >> 6;
    int tw0 = (w & 1) * 64, o0 = (w >> 1) * 64;
    int lrow = lane & 15, lgrp = lane >> 4;
    const f32x4 fz = {0.f, 0.f, 0.f, 0.f};
    f32x4 acc[4][4];
    #pragma unroll
    for (int ti = 0; ti < 4; ++ti)
        #pragma unroll
        for (int oi = 0; oi < 4; ++oi) acc[ti][oi] = fz;
    #pragma unroll
    for (int tap = 0; tap < 2; ++tap) {
        #pragma unroll
        for (int kk = 0; kk < 4; ++kk) {
            int kr = kk * 32 + lgrp * 8;
            f16x8 a[4], bw[4];
            #pragma unroll
            for (int ti = 0; ti < 4; ++ti) {
                int rrow = tw0 + ti * 16 + lrow + tap;
                a[ti] = *(const f16x8*)(yt + swzb(rrow, kr * 2));
            }
            #pragma unroll
            for (int oi = 0; oi < 4; ++oi) {
                int o = o0 + oi * 16 + lrow;
                bw[oi] = *(const f16x8*)(whc + ((size_t)tap * NCLS2 + o) * HD + kr);
            }
            #pragma unroll
            for (int ti = 0; ti < 4; ++ti)
                #pragma unroll
                for (int oi = 0; oi < 4; ++oi)
                    acc[ti][oi] = MFMA16(a[ti], bw[oi], acc[ti][oi]);
        }
    }
    const int OWM = OWLEN - 1;
    #pragma unroll
    for (int oi = 0; oi < 4; ++oi) {
        int o = o0 + oi * 16 + lrow;
        float bh = bhc[o];
        float* orow = out + ((size_t)b * NCLS2 + o) * OWM;
        #pragma unroll
        for (int ti = 0; ti < 4; ++ti) {
            int tbase = t0 + tw0 + ti * 16 + lgrp * 4;
            if (tbase + 3 < OWM) {
                f32x4u v;
                #pragma unroll
                for (int r = 0; r < 4; ++r) v[r] = acc[ti][oi][r] + bh;
                *(f32x4u*)(orow + tbase) = v;
            } else {
                #pragma unroll
                for (int r = 0; r < 4; ++r) {
                    int t = tbase + r;
                    if (t < OWM) orow[t] = acc[ti][oi][r] + bh;
                }
            }
        }
    }
}

__global__ void conv_fg_kernel(const float* __restrict__ wf, const float* __restrict__ wg,
                               f16* __restrict__ wfh, f16* __restrict__ wgh, int total)
{
    int idx = blockIdx.x * blockDim.x + threadIdx.x;
    if (idx >= total) return;
    int i = idx & 127, o = (idx >> 7) & 127, tap = (idx >> 14) & 1, j = idx >> 15;
    int src = ((j * HD + o) * HD + i) * 2 + tap;
    wfh[idx] = (f16)wf[src];
    wgh[idx] = (f16)wg[src];
}
__global__ void conv_cast_kernel(const float* __restrict__ s, f16* __restrict__ d, int n)
{
    int idx = blockIdx.x * blockDim.x + threadIdx.x;
    if (idx < n) d[idx] = (f16)s[idx];
}
__global__ void conv_whc_kernel(const float* __restrict__ s, f16* __restrict__ d)
{
    int idx = blockIdx.x * blockDim.x + threadIdx.x;
    if (idx >= 2 * NCLS2 * HD) return;
    int c = idx & 127, o = (idx >> 7) & 255, tap = idx >> 15;
    d[idx] = (f16)s[(o * HD + c) * 2 + tap];
}

extern "C" void kernel_launch(void* const* d_in, const int* in_sizes, int n_in,
                              void* d_out, int out_size, void* d_ws, size_t ws_size,
                              hipStream_t stream)
{
    const float* x     = (const float*)d_in[0];
    const float* Wf0   = (const float*)d_in[1];
    const float* bf0   = (const float*)d_in[2];
    const float* Wg0   = (const float*)d_in[3];
    const float* bg0   = (const float*)d_in[4];
    const float* W10   = (const float*)d_in[5];
    const float* b10   = (const float*)d_in[6];
    const float* Wf    = (const float*)d_in[7];
    const float* bf    = (const float*)d_in[8];
    const float* Wg    = (const float*)d_in[9];
    const float* bg    = (const float*)d_in[10];
    const float* W1    = (const float*)d_in[11];
    const float* b1    = (const float*)d_in[12];
    const float* gamma = (const float*)d_in[13];
    const float* beta  = (const float*)d_in[14];
    const float* W11   = (const float*)d_in[15];
    const float* b11   = (const float*)d_in[16];
    const float* W12   = (const float*)d_in[17];
    const float* b12   = (const float*)d_in[18];
    const float* Whc   = (const float*)d_in[19];
    const float* bhc   = (const float*)d_in[20];
    float* out = (float*)d_out;

    float* ws = (float*)d_ws;
    const size_t RN  = (size_t)NBATCH * TLEN * HD;    // residual elems (f16)
    const size_t SSN = (size_t)NBATCH * OWLEN * HD;   // skip-sum elems (fp32)

    float* ssum   = ws;
    float* gstats = ssum + SSN;
    f16* wfh  = (f16*)(gstats + NLAY * 256);
    f16* wgh  = wfh + 27 * 2 * HD * HD;
    f16* w1h  = wgh + 27 * 2 * HD * HD;
    f16* w10h = w1h + 27 * HD * HD;
    f16* w11h = w10h + HD * HD;
    f16* w12h = w11h + HD * HD;
    f16* whch = w12h + HD * HD;
    f16* rA   = whch + 2 * NCLS2 * HD;
    f16* rB   = rA + RN;

    hipMemsetAsync(gstats, 0, NLAY * 256 * sizeof(float), stream);

    {
        int total = 27 * 2 * HD * HD;
        conv_fg_kernel<<<(total + 255) / 256, 256, 0, stream>>>(Wf, Wg, wfh, wgh, total);
    }
    conv_cast_kernel<<<(27 * HD * HD + 255) / 256, 256, 0, stream>>>(W1, w1h, 27 * HD * HD);
    conv_cast_kernel<<<(HD * HD + 255) / 256, 256, 0, stream>>>(W10, w10h, HD * HD);
    conv_cast_kernel<<<(HD * HD + 255) / 256, 256, 0, stream>>>(W11, w11h, HD * HD);
    conv_cast_kernel<<<(HD * HD + 255) / 256, 256, 0, stream>>>(W12, w12h, HD * HD);
    conv_whc_kernel<<<(2 * NCLS2 * HD + 255) / 256, 256, 0, stream>>>(Whc, whch);

    dim3 lgrid(TLEN / (NT * TPB), NBATCH);   // 128 x 4 = 512 blocks
    layer0_kernel<<<lgrid, L0THR, 0, stream>>>(x, Wf0, bf0, Wg0, bg0, w10h, b10, rA, ssum, gstats);

    f16* rbufs[2] = {rA, rB};
    for (int l = 1; l < NLAY; ++l) {
        int j = l - 1;
        int dil = 1 << (l % 14);
        layer_kernel<<<lgrid, NTHR, 0, stream>>>(
            rbufs[(l - 1) & 1], rbufs[l & 1], ssum, gstats,
            wfh + (size_t)j * 2 * HD * HD, wgh + (size_t)j * 2 * HD * HD,
            w1h + (size_t)j * HD * HD,
            bf + (size_t)j * HD, bg + (size_t)j * HD, b1 + (size_t)j * HD,
            gamma + (size_t)(l - 1) * HD, beta + (size_t)(l - 1) * HD, l, dil,
            (l == NLAY - 1) ? 1 : 0);
    }

    dim3 hgrid((OWLEN + HNT - 1) / HNT, NBATCH);
    head_gemm<0><<<hgrid, HTHR, 0, stream>>>(ssum, w11h, b11, rA);
    head_gemm<1><<<hgrid, HTHR, 0, stream>>>(rA, w12h, b12, rB);
    final_kernel<<<hgrid, HTHR, 0, stream>>>(rB, whch, bhc, out);
}

// Round 15
// 2099.699 us; speedup vs baseline: 1.0074x; 1.0074x over previous
//
#include <hip/hip_runtime.h>
#include <hip/hip_fp16.h>

#define HD 128
#define TLEN 49152
#define NBATCH 4
#define NCLS2 256
#define OWLEN 16386
#define SKIP0 (TLEN - OWLEN)
#define NLAY 28
#define NT 64          // time rows per tile
#define TPB 6          // tiles per block -> grid.x = 128
#define NTHR 512       // 8 waves, each owns 16 output channels
#define L0THR 256      // layer0 stays 4-wave
#define HNT 128        // head tile
#define HTHR 512

typedef _Float16 f16;
typedef _Float16 f16x8 __attribute__((ext_vector_type(8)));
typedef _Float16 f16x4 __attribute__((ext_vector_type(4)));
typedef float f32x4 __attribute__((ext_vector_type(4)));
typedef float f32x4u __attribute__((ext_vector_type(4), aligned(4)));

#define MFMA16(a, b, c) __builtin_amdgcn_mfma_f32_16x16x32_f16(a, b, c, 0, 0, 0)

__device__ __forceinline__ float fast_tanh(float x) {
    float e = __expf(-2.f * fabsf(x));
    float t = (1.f - e) * __builtin_amdgcn_rcpf(1.f + e);
    return copysignf(t, x);
}
__device__ __forceinline__ float fast_sig(float x) {
    return __builtin_amdgcn_rcpf(1.f + __expf(-x));
}

// swizzled LDS byte offset for a [rows][128ch] f16 tile (row stride 256B)
__device__ __forceinline__ int swzb(int row, int cb) { return row * 256 + (cb ^ ((row & 7) << 4)); }

// async global->LDS, 16B/lane. LDS dest linear; swizzle via pre-swizzled per-lane
// GLOBAL source address.
__device__ __forceinline__ void gld_lds16(const void* g, void* l) {
    __builtin_amdgcn_global_load_lds((const __attribute__((address_space(1))) void*)g,
                                     (__attribute__((address_space(3))) void*)l, 16, 0, 0);
}

// wave w stages rows [w*8, w*8+8) of a 64x128 f16 tile (two 1KB issues)
__device__ __forceinline__ void stage_async(const f16* __restrict__ rb, int tbase,
                                            char* buf, int w, int lane)
{
    int rgrp = lane >> 4;
    int cb = (lane & 15) * 16;
    #pragma unroll
    for (int q = 0; q < 2; ++q) {
        int row0 = w * 8 + q * 4;
        int r = row0 + rgrp;
        int gt = tbase + r;
        const char* src = (const char*)(rb + (size_t)gt * HD) + (cb ^ ((r & 7) << 4));
        gld_lds16(src, buf + row0 * 256);
    }
}

template <int NTH>
__device__ __forceinline__ void stage_f16n(const f16* __restrict__ src, int tbase, int tlim,
                                           char* dst, int nrows)
{
    int tid = threadIdx.x;
    int cg = tid & 15;
    for (int row = tid >> 4; row < nrows; row += NTH / 16) {
        int gt = tbase + row;
        f16x8 v;
        if (gt >= 0 && gt < tlim) {
            v = *(const f16x8*)(src + (size_t)gt * HD + cg * 8);
        } else {
            #pragma unroll
            for (int i = 0; i < 8; ++i) v[i] = (f16)0.f;
        }
        *(f16x8*)(dst + swzb(row, cg * 16)) = v;
    }
}

template <int NTH>
__device__ __forceinline__ void stage_f32n(const float* __restrict__ src, int tbase, int tlim,
                                           char* dst, int nrows)
{
    int tid = threadIdx.x;
    int cg = tid & 15;
    for (int row = tid >> 4; row < nrows; row += NTH / 16) {
        int gt = tbase + row;
        f16x8 v;
        if (gt >= 0 && gt < tlim) {
            const float* p = src + (size_t)gt * HD + cg * 8;
            f32x4 a = *(const f32x4*)p;
            f32x4 b = *(const f32x4*)(p + 4);
            #pragma unroll
            for (int i = 0; i < 4; ++i) v[i] = (f16)a[i];
            #pragma unroll
            for (int i = 0; i < 4; ++i) v[4 + i] = (f16)b[i];
        } else {
            #pragma unroll
            for (int i = 0; i < 8; ++i) v[i] = (f16)0.f;
        }
        *(f16x8*)(dst + swzb(row, cg * 16)) = v;
    }
}

// dense output pass for layer kernels: rvbuf holds rv16, skbuf holds sk16.
// No affine math here (sk precomputed in R4). ro/sb per-batch bases.
template <int NTH>
__device__ __forceinline__ void dense_out2(const char* rvbuf, const char* skbuf,
                                           f16* __restrict__ ro, float* __restrict__ sb,
                                           int t0, float* s1, float* s2, int wout)
{
    int tid = threadIdx.x;
    int cg = tid & 15;
    #pragma unroll
    for (int p = 0; p < NT / (NTH / 16); ++p) {
        int row = (tid >> 4) + p * (NTH / 16);
        int gt = t0 + row;
        f16x8 rv = *(const f16x8*)(rvbuf + swzb(row, cg * 16));
        if (wout) *(f16x8*)(ro + (size_t)gt * HD + cg * 8) = rv;
        float rvf[8];
        #pragma unroll
        for (int i = 0; i < 8; ++i) {
            rvf[i] = (float)rv[i];
            s1[i] += rvf[i];
            s2[i] += rvf[i] * rvf[i];
        }
        if (gt >= SKIP0) {
            f16x8 sk = *(const f16x8*)(skbuf + swzb(row, cg * 16));
            float* sp = sb + (size_t)(gt - SKIP0) * HD + cg * 8;
            f32x4 a = *(const f32x4*)sp;
            f32x4 b2 = *(const f32x4*)(sp + 4);
            #pragma unroll
            for (int i = 0; i < 4; ++i) { a[i] += (float)sk[i]; b2[i] += (float)sk[4 + i]; }
            *(f32x4*)sp = a;
            *(f32x4*)(sp + 4) = b2;
        }
    }
}

// layer0 dense pass (skip = rv - x broadcast; ssum WRITE)
template <int NTH>
__device__ __forceinline__ void dense_out0(const char* rvbuf, const float* __restrict__ xraw,
                                           f16* __restrict__ ro, float* __restrict__ sb,
                                           int t0, float* s1, float* s2)
{
    int tid = threadIdx.x;
    int cg = tid & 15;
    #pragma unroll
    for (int p = 0; p < NT / (NTH / 16); ++p) {
        int row = (tid >> 4) + p * (NTH / 16);
        int gt = t0 + row;
        f16x8 rv = *(const f16x8*)(rvbuf + swzb(row, cg * 16));
        *(f16x8*)(ro + (size_t)gt * HD + cg * 8) = rv;
        float rvf[8];
        #pragma unroll
        for (int i = 0; i < 8; ++i) {
            rvf[i] = (float)rv[i];
            s1[i] += rvf[i];
            s2[i] += rvf[i] * rvf[i];
        }
        if (gt >= SKIP0) {
            float xv = xraw[gt];
            float* sp = sb + (size_t)(gt - SKIP0) * HD + cg * 8;
            f32x4 a, b2;
            #pragma unroll
            for (int i = 0; i < 4; ++i) { a[i] = rvf[i] - xv; b2[i] = rvf[4 + i] - xv; }
            *(f32x4*)sp = a;
            *(f32x4*)(sp + 4) = b2;
        }
    }
}

// cross-wave stats flush; NW = waves per block
template <int NW>
__device__ __forceinline__ void flush_statsN(float* s1, float* s2,
                                             float (*slds)[2][HD], float* __restrict__ gs)
{
    int tid = threadIdx.x;
    int lane = tid & 63, w = tid >> 6;
    #pragma unroll
    for (int i = 0; i < 8; ++i) {
        s1[i] += __shfl_xor(s1[i], 16); s1[i] += __shfl_xor(s1[i], 32);
        s2[i] += __shfl_xor(s2[i], 16); s2[i] += __shfl_xor(s2[i], 32);
    }
    if (lane < 16) {
        #pragma unroll
        for (int i = 0; i < 8; ++i) {
            slds[w][0][lane * 8 + i] = s1[i];
            slds[w][1][lane * 8 + i] = s2[i];
        }
    }
    __syncthreads();
    if (tid < HD) {
        float a = 0.f;
        #pragma unroll
        for (int k = 0; k < NW; ++k) a += slds[k][0][tid];
        atomicAdd(&gs[tid], a);
    } else if (tid < 2 * HD) {
        int c = tid - HD;
        float a = 0.f;
        #pragma unroll
        for (int k = 0; k < NW; ++k) a += slds[k][1][c];
        atomicAdd(&gs[HD + c], a);
    }
}

// R13 structure (plain __syncthreads, pipelined dense∥fgGEMM) + sk16-in-LDS:
// R4 stores both rv16 (bufs[cur][0]) and sk16 (bufs[cur][1], in-place over raw x),
// removing all affine math + ss loads from the dense pass.
__global__ __launch_bounds__(NTHR, 2)
void layer_kernel(const f16* __restrict__ rin, f16* __restrict__ rout,
                  float* __restrict__ ssum, float* __restrict__ gstats,
                  const f16* __restrict__ wf, const f16* __restrict__ wg,
                  const f16* __restrict__ w1,
                  const float* __restrict__ bf, const float* __restrict__ bg,
                  const float* __restrict__ b1,
                  const float* __restrict__ gamma, const float* __restrict__ beta,
                  int layer, int dil, int last)
{
    __shared__ __align__(16) char bufs[2][2][NT * 256];  // [parity][tap] 64 KB
    __shared__ float ss[256];
    __shared__ float sbias[3][HD];
    __shared__ float slds[8][2][HD];

    int tid = threadIdx.x;
    int b = blockIdx.y;

    if (tid < HD) {
        float n = (float)(NBATCH * TLEN);
        float s = gstats[(layer - 1) * 256 + tid];
        float q = gstats[(layer - 1) * 256 + 128 + tid];
        float mean = s / n;
        float var = q / n - mean * mean;
        float sc = gamma[tid] * rsqrtf(var + 1e-5f);
        ss[tid] = sc;
        ss[128 + tid] = beta[tid] - mean * sc;
        sbias[0][tid] = bf[tid];
        sbias[1][tid] = bg[tid];
        sbias[2][tid] = b1[tid];
    }
    __syncthreads();   // ss ready for weight fold

    int lane = tid & 63, w = tid >> 6;
    int m0 = w * 16;
    int lrow = lane & 15, lgrp = lane >> 4;
    const f32x4 fz = {0.f, 0.f, 0.f, 0.f};

    // load conv weights, fold BN scale into them, accumulate shift->bias corr
    f16x8 wfr[2][4], wgr[2][4], w1r[4];
    float corrF = 0.f, corrG = 0.f;
    #pragma unroll
    for (int kk = 0; kk < 4; ++kk) {
        int ck = kk * 32 + lgrp * 8;
        float scv[8], shv[8];
        #pragma unroll
        for (int i = 0; i < 8; ++i) { scv[i] = ss[ck + i]; shv[i] = ss[128 + ck + i]; }
        #pragma unroll
        for (int tap = 0; tap < 2; ++tap) {
            int o = (m0 + lrow) * HD + ck;
            f16x8 vF = *(const f16x8*)(wf + tap * HD * HD + o);
            f16x8 vG = *(const f16x8*)(wg + tap * HD * HD + o);
            #pragma unroll
            for (int i = 0; i < 8; ++i) {
                corrF += (float)vF[i] * shv[i];
                corrG += (float)vG[i] * shv[i];
                vF[i] = (f16)((float)vF[i] * scv[i]);
                vG[i] = (f16)((float)vG[i] * scv[i]);
            }
            wfr[tap][kk] = vF;
            wgr[tap][kk] = vG;
        }
        w1r[kk] = *(const f16x8*)(w1 + (m0 + lrow) * HD + ck);
    }
    corrF += __shfl_xor(corrF, 16); corrF += __shfl_xor(corrF, 32);
    corrG += __shfl_xor(corrG, 16); corrG += __shfl_xor(corrG, 32);
    if (lane < 16) {
        sbias[0][m0 + lane] += corrF;
        sbias[1][m0 + lane] += corrG;
    }

    const f16* rb = rin + (size_t)b * TLEN * HD;
    f16* ro = rout + (size_t)b * TLEN * HD;
    float* sb = ssum + (size_t)b * OWLEN * HD;

    float s1[8] = {}, s2[8] = {};
    int tb = blockIdx.x * TPB * NT;
    int c0 = m0 + lgrp * 4;
    int cg = tid & 15;

    // per-thread causal pad value (raw value whose normalized form is 0)
    float padv[8];
    #pragma unroll
    for (int i = 0; i < 8; ++i)
        padv[i] = -ss[128 + cg * 8 + i] * __builtin_amdgcn_rcpf(ss[cg * 8 + i]);

    // prologue: issue tile-0 stage (raw)
    stage_async(rb, tb, bufs[0][1], w, lane);
    stage_async(rb, tb - dil, bufs[0][0], w, lane);

    for (int ti = 0; ti < TPB; ++ti) {
        int t0 = tb + ti * NT;
        int cur = ti & 1;
        int prv = cur ^ 1;
        __syncthreads();   // B0: staged tiles landed + rv/sk writes(ti-1) visible

        // causal boundary patch: padded positions get padv (normalized -> 0)
        if (t0 < dil) {
            for (int r0 = tid >> 4; r0 < NT; r0 += NTHR / 16) {
                if (t0 - dil + r0 < 0) {
                    f16x8 v;
                    #pragma unroll
                    for (int i = 0; i < 8; ++i) v[i] = (f16)padv[i];
                    *(f16x8*)(bufs[cur][0] + swzb(r0, cg * 16)) = v;
                }
            }
            __syncthreads();
        }

        // R1: dense_out(t-1) [parity prv] ∥ fg GEMM(t) [parity cur]
        if (ti > 0)
            dense_out2<NTHR>(bufs[prv][0], bufs[prv][1], ro, sb, t0 - NT, s1, s2, !last);

        f32x4 facc[4], gacc[4];
        #pragma unroll
        for (int ni = 0; ni < 4; ++ni) { facc[ni] = fz; gacc[ni] = fz; }
        #pragma unroll
        for (int tap = 0; tap < 2; ++tap) {
            const char* xt = bufs[cur][tap];
            #pragma unroll
            for (int kk = 0; kk < 4; ++kk) {
                f16x8 bx[4];
                #pragma unroll
                for (int ni = 0; ni < 4; ++ni)
                    bx[ni] = *(const f16x8*)(xt + swzb(ni * 16 + lrow, (kk * 32 + lgrp * 8) * 2));
                #pragma unroll
                for (int ni = 0; ni < 4; ++ni) {
                    facc[ni] = MFMA16(wfr[tap][kk], bx[ni], facc[ni]);
                    gacc[ni] = MFMA16(wgr[tap][kk], bx[ni], gacc[ni]);
                }
            }
        }
        __syncthreads();   // B1: tap reads + dense's prv LDS reads done

        // R2: issue stage(t+1) into prv parity; gate-write h into bufs[cur][0]
        if (ti + 1 < TPB) {
            stage_async(rb, t0 + NT, bufs[prv][1], w, lane);
            stage_async(rb, t0 + NT - dil, bufs[prv][0], w, lane);
        }
        {
            float bfv[4], bgv[4];
            #pragma unroll
            for (int r = 0; r < 4; ++r) { bfv[r] = sbias[0][c0 + r]; bgv[r] = sbias[1][c0 + r]; }
            #pragma unroll
            for (int ni = 0; ni < 4; ++ni) {
                int t = ni * 16 + lrow;
                f16x4 hv;
                #pragma unroll
                for (int r = 0; r < 4; ++r) {
                    float fv = facc[ni][r] + bfv[r];
                    float gv = gacc[ni][r] + bgv[r];
                    hv[r] = (f16)(fast_tanh(fv) * fast_sig(gv));
                }
                *(f16x4*)(bufs[cur][0] + swzb(t, c0 * 2)) = hv;
            }
        }
        __syncthreads();   // B2: h writes visible

        // R3: W1 GEMM, weights from registers
        f32x4 sacc[4];
        #pragma unroll
        for (int ni = 0; ni < 4; ++ni) sacc[ni] = fz;
        #pragma unroll
        for (int kk = 0; kk < 4; ++kk) {
            int cb = (kk * 32 + lgrp * 8) * 2;
            f16x8 bx[4];
            #pragma unroll
            for (int ni = 0; ni < 4; ++ni)
                bx[ni] = *(const f16x8*)(bufs[cur][0] + swzb(ni * 16 + lrow, cb));
            #pragma unroll
            for (int ni = 0; ni < 4; ++ni)
                sacc[ni] = MFMA16(w1r[kk], bx[ni], sacc[ni]);
        }
        __syncthreads();   // B3: h reads done

        // R4: sk = sacc + b1; rv = sk + affine(raw x).
        // rv16 -> bufs[cur][0] (over h); sk16 -> bufs[cur][1] (in place over raw x;
        // each thread rewrites exactly the bytes it read -> no extra barrier).
        {
            float bb[4], sc0[4], sh0[4];
            #pragma unroll
            for (int r = 0; r < 4; ++r) {
                bb[r] = sbias[2][c0 + r];
                sc0[r] = ss[c0 + r];
                sh0[r] = ss[128 + c0 + r];
            }
            #pragma unroll
            for (int ni = 0; ni < 4; ++ni) {
                int tl = ni * 16 + lrow;
                f16x4 xv = *(const f16x4*)(bufs[cur][1] + swzb(tl, c0 * 2));  // RAW
                f16x4 rv16, sk16;
                #pragma unroll
                for (int r = 0; r < 4; ++r) {
                    float sk = sacc[ni][r] + bb[r];
                    sk16[r] = (f16)sk;
                    rv16[r] = (f16)(sk + ((float)xv[r] * sc0[r] + sh0[r]));
                }
                *(f16x4*)(bufs[cur][0] + swzb(tl, c0 * 2)) = rv16;
                *(f16x4*)(bufs[cur][1] + swzb(tl, c0 * 2)) = sk16;
            }
        }
        // loop -> B0
    }

    __syncthreads();
    dense_out2<NTHR>(bufs[(TPB - 1) & 1][0], bufs[(TPB - 1) & 1][1],
                     ro, sb, tb + (TPB - 1) * NT, s1, s2, !last);

    if (!last) flush_statsN<8>(s1, s2, slds, gstats + layer * 256);
}

__global__ __launch_bounds__(L0THR, 4)
void layer0_kernel(const float* __restrict__ x,
                   const float* __restrict__ Wf0, const float* __restrict__ bf0,
                   const float* __restrict__ Wg0, const float* __restrict__ bg0,
                   const f16* __restrict__ w10, const float* __restrict__ b10,
                   f16* __restrict__ rout, float* __restrict__ ssum,
                   float* __restrict__ gstats)
{
    __shared__ __align__(16) char hbuf[NT * 256];
    __shared__ __align__(16) char w1s[32768];
    __shared__ float wl[6][HD];
    __shared__ float slds0[4][2][HD];
    int tid = threadIdx.x;
    int b = blockIdx.y;
    if (tid < HD) {
        wl[0][tid] = Wf0[tid * 2 + 0]; wl[1][tid] = Wf0[tid * 2 + 1]; wl[2][tid] = bf0[tid];
        wl[3][tid] = Wg0[tid * 2 + 0]; wl[4][tid] = Wg0[tid * 2 + 1]; wl[5][tid] = bg0[tid];
    }
    {
        int cg = tid & 15;
        #pragma unroll
        for (int p = 0; p < 8; ++p) {
            int row = (tid >> 4) + p * 16;
            f16x8 v = *(const f16x8*)(w10 + row * HD + cg * 8);
            *(f16x8*)(w1s + swzb(row, cg * 16)) = v;
        }
    }
    __syncthreads();
    const float* xb = x + (size_t)b * TLEN;
    f16* ro = rout + (size_t)b * TLEN * HD;
    float* sb = ssum + (size_t)b * OWLEN * HD;
    int cg = tid & 15;
    int lane = tid & 63, w = tid >> 6;
    int m0 = w * 32;
    int lrow = lane & 15, lgrp = lane >> 4;
    const f32x4 fz = {0.f, 0.f, 0.f, 0.f};
    float s1[8] = {}, s2[8] = {};

    for (int ti = 0; ti < TPB; ++ti) {
        int t0 = (blockIdx.x * TPB + ti) * NT;
        if (ti) __syncthreads();
        #pragma unroll
        for (int p = 0; p < NT / 16; ++p) {
            int row = (tid >> 4) + p * 16;
            int gt = t0 + row;
            float xc = xb[gt];
            float xm = (gt >= 1) ? xb[gt - 1] : 0.f;
            f16x8 hv;
            #pragma unroll
            for (int i = 0; i < 8; ++i) {
                int c = cg * 8 + i;
                float fv = wl[0][c] * xm + wl[1][c] * xc + wl[2][c];
                float gv = wl[3][c] * xm + wl[4][c] * xc + wl[5][c];
                hv[i] = (f16)(fast_tanh(fv) * fast_sig(gv));
            }
            *(f16x8*)(hbuf + swzb(row, cg * 16)) = hv;
        }
        __syncthreads();

        f32x4 sacc[2][4];
        #pragma unroll
        for (int mi = 0; mi < 2; ++mi)
            #pragma unroll
            for (int ni = 0; ni < 4; ++ni) sacc[mi][ni] = fz;
        #pragma unroll
        for (int kk = 0; kk < 4; ++kk) {
            int cb = (kk * 32 + lgrp * 8) * 2;
            f16x8 a[2], bx[4];
            #pragma unroll
            for (int mi = 0; mi < 2; ++mi)
                a[mi] = *(const f16x8*)(w1s + swzb(m0 + mi * 16 + lrow, cb));
            #pragma unroll
            for (int ni = 0; ni < 4; ++ni)
                bx[ni] = *(const f16x8*)(hbuf + swzb(ni * 16 + lrow, cb));
            #pragma unroll
            for (int mi = 0; mi < 2; ++mi)
                #pragma unroll
                for (int ni = 0; ni < 4; ++ni)
                    sacc[mi][ni] = MFMA16(a[mi], bx[ni], sacc[mi][ni]);
        }
        __syncthreads();

        #pragma unroll
        for (int mi = 0; mi < 2; ++mi) {
            int c0 = m0 + mi * 16 + lgrp * 4;
            float bb[4];
            #pragma unroll
            for (int r = 0; r < 4; ++r) bb[r] = b10[c0 + r];
            #pragma unroll
            for (int ni = 0; ni < 4; ++ni) {
                int tl = ni * 16 + lrow;
                float xn = xb[t0 + tl];
                f16x4 rv16;
                #pragma unroll
                for (int r = 0; r < 4; ++r)
                    rv16[r] = (f16)(sacc[mi][ni][r] + bb[r] + xn);
                *(f16x4*)(hbuf + swzb(tl, c0 * 2)) = rv16;
            }
        }
        __syncthreads();
        dense_out0<L0THR>(hbuf, xb, ro, sb, t0, s1, s2);
    }
    flush_statsN<4>(s1, s2, slds0, gstats);
}

template <int SRC16>
__global__ __launch_bounds__(HTHR)
void head_gemm(const void* __restrict__ in, const f16* __restrict__ wm,
               const float* __restrict__ bias, f16* __restrict__ out)
{
    __shared__ __align__(16) char xt[HNT * 256];
    int tid = threadIdx.x;
    int b = blockIdx.y;
    int t0 = blockIdx.x * HNT;
    if (SRC16)
        stage_f16n<HTHR>((const f16*)in + (size_t)b * OWLEN * HD, t0, OWLEN, xt, HNT);
    else
        stage_f32n<HTHR>((const float*)in + (size_t)b * OWLEN * HD, t0, OWLEN, xt, HNT);
    __syncthreads();
    int lane = tid & 63, w = tid >> 6;
    int m0 = (w >> 1) * 32, n0 = (w & 1) * 64;
    int lrow = lane & 15, lgrp = lane >> 4;
    const f32x4 fz = {0.f, 0.f, 0.f, 0.f};
    f32x4 acc[2][4];
    #pragma unroll
    for (int mi = 0; mi < 2; ++mi)
        #pragma unroll
        for (int ni = 0; ni < 4; ++ni) acc[mi][ni] = fz;
    #pragma unroll
    for (int kk = 0; kk < 4; ++kk) {
        int kr = kk * 32 + lgrp * 8;
        f16x8 a[2], bx[4];
        #pragma unroll
        for (int mi = 0; mi < 2; ++mi)
            a[mi] = *(const f16x8*)(wm + (m0 + mi * 16 + lrow) * HD + kr);
        #pragma unroll
        for (int ni = 0; ni < 4; ++ni)
            bx[ni] = *(const f16x8*)(xt + swzb(n0 + ni * 16 + lrow, kr * 2));
        #pragma unroll
        for (int mi = 0; mi < 2; ++mi)
            #pragma unroll
            for (int ni = 0; ni < 4; ++ni)
                acc[mi][ni] = MFMA16(a[mi], bx[ni], acc[mi][ni]);
    }
    __syncthreads();   // xt reads done; reuse for relu output
    #pragma unroll
    for (int mi = 0; mi < 2; ++mi) {
        int c0 = m0 + mi * 16 + lgrp * 4;
        float bv[4];
        #pragma unroll
        for (int r = 0; r < 4; ++r) bv[r] = bias[c0 + r];
        #pragma unroll
        for (int ni = 0; ni < 4; ++ni) {
            int tl = n0 + ni * 16 + lrow;
            f16x4 v;
            #pragma unroll
            for (int r = 0; r < 4; ++r) v[r] = (f16)fmaxf(acc[mi][ni][r] + bv[r], 0.f);
            *(f16x4*)(xt + swzb(tl, c0 * 2)) = v;
        }
    }
    __syncthreads();
    f16* ob = out + (size_t)b * OWLEN * HD;
    int cg = tid & 15;
    #pragma unroll
    for (int p = 0; p < HNT / 32; ++p) {
        int row = (tid >> 4) + p * 32;
        int gt = t0 + row;
        if (gt < OWLEN) {
            f16x8 v = *(const f16x8*)(xt + swzb(row, cg * 16));
            *(f16x8*)(ob + (size_t)gt * HD + cg * 8) = v;
        }
    }
}

__global__ __launch_bounds__(HTHR)
void final_kernel(const f16* __restrict__ y2, const f16* __restrict__ whc,
                  const float* __restrict__ bhc, float* __restrict__ out)
{
    __shared__ __align__(16) char yt[130 * 256];
    int tid = threadIdx.x;
    int b = blockIdx.y;
    int t0 = blockIdx.x * HNT;
    stage_f16n<HTHR>(y2 + (size_t)b * OWLEN * HD, t0, OWLEN, yt, 130);
    __syncthreads();
    int lane = tid & 63, w = tid >> 6;
    int tw0 = (w & 1) * 64, o0 = (w >> 1) * 64;
    int lrow = lane & 15, lgrp = lane >> 4;
    const f32x4 fz = {0.f, 0.f, 0.f, 0.f};
    f32x4 acc[4][4];
    #pragma unroll
    for (int ti = 0; ti < 4; ++ti)
        #pragma unroll
        for (int oi = 0; oi < 4; ++oi) acc[ti][oi] = fz;
    #pragma unroll
    for (int tap = 0; tap < 2; ++tap) {
        #pragma unroll
        for (int kk = 0; kk < 4; ++kk) {
            int kr = kk * 32 + lgrp * 8;
            f16x8 a[4], bw[4];
            #pragma unroll
            for (int ti = 0; ti < 4; ++ti) {
                int rrow = tw0 + ti * 16 + lrow + tap;
                a[ti] = *(const f16x8*)(yt + swzb(rrow, kr * 2));
            }
            #pragma unroll
            for (int oi = 0; oi < 4; ++oi) {
                int o = o0 + oi * 16 + lrow;
                bw[oi] = *(const f16x8*)(whc + ((size_t)tap * NCLS2 + o) * HD + kr);
            }
            #pragma unroll
            for (int ti = 0; ti < 4; ++ti)
                #pragma unroll
                for (int oi = 0; oi < 4; ++oi)
                    acc[ti][oi] = MFMA16(a[ti], bw[oi], acc[ti][oi]);
        }
    }
    const int OWM = OWLEN - 1;
    #pragma unroll
    for (int oi = 0; oi < 4; ++oi) {
        int o = o0 + oi * 16 + lrow;
        float bh = bhc[o];
        float* orow = out + ((size_t)b * NCLS2 + o) * OWM;
        #pragma unroll
        for (int ti = 0; ti < 4; ++ti) {
            int tbase = t0 + tw0 + ti * 16 + lgrp * 4;
            if (tbase + 3 < OWM) {
                f32x4u v;
                #pragma unroll
                for (int r = 0; r < 4; ++r) v[r] = acc[ti][oi][r] + bh;
                *(f32x4u*)(orow + tbase) = v;
            } else {
                #pragma unroll
                for (int r = 0; r < 4; ++r) {
                    int t = tbase + r;
                    if (t < OWM) orow[t] = acc[ti][oi][r] + bh;
                }
            }
        }
    }
}

__global__ void conv_fg_kernel(const float* __restrict__ wf, const float* __restrict__ wg,
                               f16* __restrict__ wfh, f16* __restrict__ wgh, int total)
{
    int idx = blockIdx.x * blockDim.x + threadIdx.x;
    if (idx >= total) return;
    int i = idx & 127, o = (idx >> 7) & 127, tap = (idx >> 14) & 1, j = idx >> 15;
    int src = ((j * HD + o) * HD + i) * 2 + tap;
    wfh[idx] = (f16)wf[src];
    wgh[idx] = (f16)wg[src];
}
__global__ void conv_cast_kernel(const float* __restrict__ s, f16* __restrict__ d, int n)
{
    int idx = blockIdx.x * blockDim.x + threadIdx.x;
    if (idx < n) d[idx] = (f16)s[idx];
}
__global__ void conv_whc_kernel(const float* __restrict__ s, f16* __restrict__ d)
{
    int idx = blockIdx.x * blockDim.x + threadIdx.x;
    if (idx >= 2 * NCLS2 * HD) return;
    int c = idx & 127, o = (idx >> 7) & 255, tap = idx >> 15;
    d[idx] = (f16)s[(o * HD + c) * 2 + tap];
}

extern "C" void kernel_launch(void* const* d_in, const int* in_sizes, int n_in,
                              void* d_out, int out_size, void* d_ws, size_t ws_size,
                              hipStream_t stream)
{
    const float* x     = (const float*)d_in[0];
    const float* Wf0   = (const float*)d_in[1];
    const float* bf0   = (const float*)d_in[2];
    const float* Wg0   = (const float*)d_in[3];
    const float* bg0   = (const float*)d_in[4];
    const float* W10   = (const float*)d_in[5];
    const float* b10   = (const float*)d_in[6];
    const float* Wf    = (const float*)d_in[7];
    const float* bf    = (const float*)d_in[8];
    const float* Wg    = (const float*)d_in[9];
    const float* bg    = (const float*)d_in[10];
    const float* W1    = (const float*)d_in[11];
    const float* b1    = (const float*)d_in[12];
    const float* gamma = (const float*)d_in[13];
    const float* beta  = (const float*)d_in[14];
    const float* W11   = (const float*)d_in[15];
    const float* b11   = (const float*)d_in[16];
    const float* W12   = (const float*)d_in[17];
    const float* b12   = (const float*)d_in[18];
    const float* Whc   = (const float*)d_in[19];
    const float* bhc   = (const float*)d_in[20];
    float* out = (float*)d_out;

    float* ws = (float*)d_ws;
    const size_t RN  = (size_t)NBATCH * TLEN * HD;    // residual elems (f16)
    const size_t SSN = (size_t)NBATCH * OWLEN * HD;   // skip-sum elems (fp32)

    float* ssum   = ws;
    float* gstats = ssum + SSN;
    f16* wfh  = (f16*)(gstats + NLAY * 256);
    f16* wgh  = wfh + 27 * 2 * HD * HD;
    f16* w1h  = wgh + 27 * 2 * HD * HD;
    f16* w10h = w1h + 27 * HD * HD;
    f16* w11h = w10h + HD * HD;
    f16* w12h = w11h + HD * HD;
    f16* whch = w12h + HD * HD;
    f16* rA   = whch + 2 * NCLS2 * HD;
    f16* rB   = rA + RN;

    hipMemsetAsync(gstats, 0, NLAY * 256 * sizeof(float), stream);

    {
        int total = 27 * 2 * HD * HD;
        conv_fg_kernel<<<(total + 255) / 256, 256, 0, stream>>>(Wf, Wg, wfh, wgh, total);
    }
    conv_cast_kernel<<<(27 * HD * HD + 255) / 256, 256, 0, stream>>>(W1, w1h, 27 * HD * HD);
    conv_cast_kernel<<<(HD * HD + 255) / 256, 256, 0, stream>>>(W10, w10h, HD * HD);
    conv_cast_kernel<<<(HD * HD + 255) / 256, 256, 0, stream>>>(W11, w11h, HD * HD);
    conv_cast_kernel<<<(HD * HD + 255) / 256, 256, 0, stream>>>(W12, w12h, HD * HD);
    conv_whc_kernel<<<(2 * NCLS2 * HD + 255) / 256, 256, 0, stream>>>(Whc, whch);

    dim3 lgrid(TLEN / (NT * TPB), NBATCH);   // 128 x 4 = 512 blocks
    layer0_kernel<<<lgrid, L0THR, 0, stream>>>(x, Wf0, bf0, Wg0, bg0, w10h, b10, rA, ssum, gstats);

    f16* rbufs[2] = {rA, rB};
    for (int l = 1; l < NLAY; ++l) {
        int j = l - 1;
        int dil = 1 << (l % 14);
        layer_kernel<<<lgrid, NTHR, 0, stream>>>(
            rbufs[(l - 1) & 1], rbufs[l & 1], ssum, gstats,
            wfh + (size_t)j * 2 * HD * HD, wgh + (size_t)j * 2 * HD * HD,
            w1h + (size_t)j * HD * HD,
            bf + (size_t)j * HD, bg + (size_t)j * HD, b1 + (size_t)j * HD,
            gamma + (size_t)(l - 1) * HD, beta + (size_t)(l - 1) * HD, l, dil,
            (l == NLAY - 1) ? 1 : 0);
    }

    dim3 hgrid((OWLEN + HNT - 1) / HNT, NBATCH);
    head_gemm<0><<<hgrid, HTHR, 0, stream>>>(ssum, w11h, b11, rA);
    head_gemm<1><<<hgrid, HTHR, 0, stream>>>(rA, w12h, b12, rB);
    final_kernel<<<hgrid, HTHR, 0, stream>>>(rB, whch, bhc, out);
}

// Round 16
// 1927.378 us; speedup vs baseline: 1.0974x; 1.0894x over previous
//
#include <hip/hip_runtime.h>
#include <hip/hip_fp16.h>

#define HD 128
#define TLEN 49152
#define NBATCH 4
#define NCLS2 256
#define OWLEN 16386
#define SKIP0 (TLEN - OWLEN)
#define NLAY 28
#define NT 64          // time rows per tile
#define TPB 6          // tiles per block -> grid.x = 128
#define NTHR 512       // 8 waves, each owns 16 output channels
#define L0THR 256      // layer0 stays 4-wave
#define HNT 128        // head tile
#define HTHR 512

typedef _Float16 f16;
typedef _Float16 f16x8 __attribute__((ext_vector_type(8)));
typedef _Float16 f16x4 __attribute__((ext_vector_type(4)));
typedef float f32x4 __attribute__((ext_vector_type(4)));
typedef float f32x4u __attribute__((ext_vector_type(4), aligned(4)));

#define MFMA16(a, b, c) __builtin_amdgcn_mfma_f32_16x16x32_f16(a, b, c, 0, 0, 0)

// fused tanh(f)*sigmoid(g) = sign(f)*(1-u)*rcp((1+u)*(1+v)), u=e^{-2|f|}, v=e^{-g}
__device__ __forceinline__ float gate_ts(float fv, float gv) {
    float u = __expf(-2.f * fabsf(fv));
    float v = __expf(-gv);
    float num = copysignf(1.f - u, fv);
    return num * __builtin_amdgcn_rcpf((1.f + u) * (1.f + v));
}

// swizzled LDS byte offset for a [rows][128ch] f16 tile (row stride 256B)
__device__ __forceinline__ int swzb(int row, int cb) { return row * 256 + (cb ^ ((row & 7) << 4)); }

// async global->LDS, 16B/lane. LDS dest linear; swizzle via pre-swizzled per-lane
// GLOBAL source address.
__device__ __forceinline__ void gld_lds16(const void* g, void* l) {
    __builtin_amdgcn_global_load_lds((const __attribute__((address_space(1))) void*)g,
                                     (__attribute__((address_space(3))) void*)l, 16, 0, 0);
}

// wave w stages rows [w*8, w*8+8) of a 64x128 f16 tile (two 1KB issues)
__device__ __forceinline__ void stage_async(const f16* __restrict__ rb, int tbase,
                                            char* buf, int w, int lane)
{
    int rgrp = lane >> 4;
    int cb = (lane & 15) * 16;
    #pragma unroll
    for (int q = 0; q < 2; ++q) {
        int row0 = w * 8 + q * 4;
        int r = row0 + rgrp;
        int gt = tbase + r;
        const char* src = (const char*)(rb + (size_t)gt * HD) + (cb ^ ((r & 7) << 4));
        gld_lds16(src, buf + row0 * 256);
    }
}

template <int NTH>
__device__ __forceinline__ void stage_f16n(const f16* __restrict__ src, int tbase, int tlim,
                                           char* dst, int nrows)
{
    int tid = threadIdx.x;
    int cg = tid & 15;
    for (int row = tid >> 4; row < nrows; row += NTH / 16) {
        int gt = tbase + row;
        f16x8 v;
        if (gt >= 0 && gt < tlim) {
            v = *(const f16x8*)(src + (size_t)gt * HD + cg * 8);
        } else {
            #pragma unroll
            for (int i = 0; i < 8; ++i) v[i] = (f16)0.f;
        }
        *(f16x8*)(dst + swzb(row, cg * 16)) = v;
    }
}

// dense output pass for layer kernels: rvbuf holds rv16, skbuf holds sk16.
// ssum is f16 (RMW with fp32 intermediate math).
template <int NTH>
__device__ __forceinline__ void dense_out2(const char* rvbuf, const char* skbuf,
                                           f16* __restrict__ ro, f16* __restrict__ sb,
                                           int t0, float* s1, float* s2, int wout)
{
    int tid = threadIdx.x;
    int cg = tid & 15;
    #pragma unroll
    for (int p = 0; p < NT / (NTH / 16); ++p) {
        int row = (tid >> 4) + p * (NTH / 16);
        int gt = t0 + row;
        f16x8 rv = *(const f16x8*)(rvbuf + swzb(row, cg * 16));
        if (wout) *(f16x8*)(ro + (size_t)gt * HD + cg * 8) = rv;
        float rvf[8];
        #pragma unroll
        for (int i = 0; i < 8; ++i) {
            rvf[i] = (float)rv[i];
            s1[i] += rvf[i];
            s2[i] += rvf[i] * rvf[i];
        }
        if (gt >= SKIP0) {
            f16x8 sk = *(const f16x8*)(skbuf + swzb(row, cg * 16));
            f16* sp = sb + (size_t)(gt - SKIP0) * HD + cg * 8;
            f16x8 s0 = *(const f16x8*)sp;
            #pragma unroll
            for (int i = 0; i < 8; ++i)
                s0[i] = (f16)((float)s0[i] + (float)sk[i]);
            *(f16x8*)sp = s0;
        }
    }
}

// layer0 dense pass (skip = rv - x broadcast; ssum WRITE, f16)
template <int NTH>
__device__ __forceinline__ void dense_out0(const char* rvbuf, const float* __restrict__ xraw,
                                           f16* __restrict__ ro, f16* __restrict__ sb,
                                           int t0, float* s1, float* s2)
{
    int tid = threadIdx.x;
    int cg = tid & 15;
    #pragma unroll
    for (int p = 0; p < NT / (NTH / 16); ++p) {
        int row = (tid >> 4) + p * (NTH / 16);
        int gt = t0 + row;
        f16x8 rv = *(const f16x8*)(rvbuf + swzb(row, cg * 16));
        *(f16x8*)(ro + (size_t)gt * HD + cg * 8) = rv;
        float rvf[8];
        #pragma unroll
        for (int i = 0; i < 8; ++i) {
            rvf[i] = (float)rv[i];
            s1[i] += rvf[i];
            s2[i] += rvf[i] * rvf[i];
        }
        if (gt >= SKIP0) {
            float xv = xraw[gt];
            f16* sp = sb + (size_t)(gt - SKIP0) * HD + cg * 8;
            f16x8 s0;
            #pragma unroll
            for (int i = 0; i < 8; ++i) s0[i] = (f16)(rvf[i] - xv);
            *(f16x8*)sp = s0;
        }
    }
}

// cross-wave stats flush; NW = waves per block
template <int NW>
__device__ __forceinline__ void flush_statsN(float* s1, float* s2,
                                             float (*slds)[2][HD], float* __restrict__ gs)
{
    int tid = threadIdx.x;
    int lane = tid & 63, w = tid >> 6;
    #pragma unroll
    for (int i = 0; i < 8; ++i) {
        s1[i] += __shfl_xor(s1[i], 16); s1[i] += __shfl_xor(s1[i], 32);
        s2[i] += __shfl_xor(s2[i], 16); s2[i] += __shfl_xor(s2[i], 32);
    }
    if (lane < 16) {
        #pragma unroll
        for (int i = 0; i < 8; ++i) {
            slds[w][0][lane * 8 + i] = s1[i];
            slds[w][1][lane * 8 + i] = s2[i];
        }
    }
    __syncthreads();
    if (tid < HD) {
        float a = 0.f;
        #pragma unroll
        for (int k = 0; k < NW; ++k) a += slds[k][0][tid];
        atomicAdd(&gs[tid], a);
    } else if (tid < 2 * HD) {
        int c = tid - HD;
        float a = 0.f;
        #pragma unroll
        for (int k = 0; k < NW; ++k) a += slds[k][1][c];
        atomicAdd(&gs[HD + c], a);
    }
}

__global__ __launch_bounds__(NTHR, 2)
void layer_kernel(const f16* __restrict__ rin, f16* __restrict__ rout,
                  f16* __restrict__ ssum, float* __restrict__ gstats,
                  const f16* __restrict__ wf, const f16* __restrict__ wg,
                  const f16* __restrict__ w1,
                  const float* __restrict__ bf, const float* __restrict__ bg,
                  const float* __restrict__ b1,
                  const float* __restrict__ gamma, const float* __restrict__ beta,
                  int layer, int dil, int last)
{
    __shared__ __align__(16) char bufs[2][2][NT * 256];  // [parity][tap] 64 KB
    __shared__ float ss[256];
    __shared__ float sbias[3][HD];
    __shared__ float slds[8][2][HD];

    int tid = threadIdx.x;
    int b = blockIdx.y;

    if (tid < HD) {
        float n = (float)(NBATCH * TLEN);
        float s = gstats[(layer - 1) * 256 + tid];
        float q = gstats[(layer - 1) * 256 + 128 + tid];
        float mean = s / n;
        float var = q / n - mean * mean;
        float sc = gamma[tid] * rsqrtf(var + 1e-5f);
        ss[tid] = sc;
        ss[128 + tid] = beta[tid] - mean * sc;
        sbias[0][tid] = bf[tid];
        sbias[1][tid] = bg[tid];
        sbias[2][tid] = b1[tid];
    }
    __syncthreads();   // ss ready for weight fold

    int lane = tid & 63, w = tid >> 6;
    int m0 = w * 16;
    int lrow = lane & 15, lgrp = lane >> 4;
    const f32x4 fz = {0.f, 0.f, 0.f, 0.f};

    // load conv weights, fold BN scale into them, accumulate shift->bias corr
    f16x8 wfr[2][4], wgr[2][4], w1r[4];
    float corrF = 0.f, corrG = 0.f;
    #pragma unroll
    for (int kk = 0; kk < 4; ++kk) {
        int ck = kk * 32 + lgrp * 8;
        float scv[8], shv[8];
        #pragma unroll
        for (int i = 0; i < 8; ++i) { scv[i] = ss[ck + i]; shv[i] = ss[128 + ck + i]; }
        #pragma unroll
        for (int tap = 0; tap < 2; ++tap) {
            int o = (m0 + lrow) * HD + ck;
            f16x8 vF = *(const f16x8*)(wf + tap * HD * HD + o);
            f16x8 vG = *(const f16x8*)(wg + tap * HD * HD + o);
            #pragma unroll
            for (int i = 0; i < 8; ++i) {
                corrF += (float)vF[i] * shv[i];
                corrG += (float)vG[i] * shv[i];
                vF[i] = (f16)((float)vF[i] * scv[i]);
                vG[i] = (f16)((float)vG[i] * scv[i]);
            }
            wfr[tap][kk] = vF;
            wgr[tap][kk] = vG;
        }
        w1r[kk] = *(const f16x8*)(w1 + (m0 + lrow) * HD + ck);
    }
    corrF += __shfl_xor(corrF, 16); corrF += __shfl_xor(corrF, 32);
    corrG += __shfl_xor(corrG, 16); corrG += __shfl_xor(corrG, 32);
    if (lane < 16) {
        sbias[0][m0 + lane] += corrF;
        sbias[1][m0 + lane] += corrG;
    }

    const f16* rb = rin + (size_t)b * TLEN * HD;
    f16* ro = rout + (size_t)b * TLEN * HD;
    f16* sb = ssum + (size_t)b * OWLEN * HD;

    float s1[8] = {}, s2[8] = {};
    int tb = blockIdx.x * TPB * NT;
    int c0 = m0 + lgrp * 4;
    int cg = tid & 15;

    // per-thread causal pad value (raw value whose normalized form is 0)
    float padv[8];
    #pragma unroll
    for (int i = 0; i < 8; ++i)
        padv[i] = -ss[128 + cg * 8 + i] * __builtin_amdgcn_rcpf(ss[cg * 8 + i]);

    // prologue: issue tile-0 stage (raw)
    stage_async(rb, tb, bufs[0][1], w, lane);
    stage_async(rb, tb - dil, bufs[0][0], w, lane);

    for (int ti = 0; ti < TPB; ++ti) {
        int t0 = tb + ti * NT;
        int cur = ti & 1;
        int prv = cur ^ 1;
        __syncthreads();   // B0: staged tiles landed + rv/sk writes(ti-1) visible

        // causal boundary patch: padded positions get padv (normalized -> 0)
        if (t0 < dil) {
            for (int r0 = tid >> 4; r0 < NT; r0 += NTHR / 16) {
                if (t0 - dil + r0 < 0) {
                    f16x8 v;
                    #pragma unroll
                    for (int i = 0; i < 8; ++i) v[i] = (f16)padv[i];
                    *(f16x8*)(bufs[cur][0] + swzb(r0, cg * 16)) = v;
                }
            }
            __syncthreads();
        }

        // R1: dense_out(t-1) [parity prv] ∥ fg GEMM(t) [parity cur]
        if (ti > 0)
            dense_out2<NTHR>(bufs[prv][0], bufs[prv][1], ro, sb, t0 - NT, s1, s2, !last);

        f32x4 facc[4], gacc[4];
        #pragma unroll
        for (int ni = 0; ni < 4; ++ni) { facc[ni] = fz; gacc[ni] = fz; }
        #pragma unroll
        for (int tap = 0; tap < 2; ++tap) {
            const char* xt = bufs[cur][tap];
            #pragma unroll
            for (int kk = 0; kk < 4; ++kk) {
                f16x8 bx[4];
                #pragma unroll
                for (int ni = 0; ni < 4; ++ni)
                    bx[ni] = *(const f16x8*)(xt + swzb(ni * 16 + lrow, (kk * 32 + lgrp * 8) * 2));
                #pragma unroll
                for (int ni = 0; ni < 4; ++ni) {
                    facc[ni] = MFMA16(wfr[tap][kk], bx[ni], facc[ni]);
                    gacc[ni] = MFMA16(wgr[tap][kk], bx[ni], gacc[ni]);
                }
            }
        }
        __syncthreads();   // B1: tap reads + dense's prv LDS reads done

        // R2: issue stage(t+1) into prv parity; gate-write h into bufs[cur][0]
        if (ti + 1 < TPB) {
            stage_async(rb, t0 + NT, bufs[prv][1], w, lane);
            stage_async(rb, t0 + NT - dil, bufs[prv][0], w, lane);
        }
        {
            float bfv[4], bgv[4];
            #pragma unroll
            for (int r = 0; r < 4; ++r) { bfv[r] = sbias[0][c0 + r]; bgv[r] = sbias[1][c0 + r]; }
            #pragma unroll
            for (int ni = 0; ni < 4; ++ni) {
                int t = ni * 16 + lrow;
                f16x4 hv;
                #pragma unroll
                for (int r = 0; r < 4; ++r)
                    hv[r] = (f16)gate_ts(facc[ni][r] + bfv[r], gacc[ni][r] + bgv[r]);
                *(f16x4*)(bufs[cur][0] + swzb(t, c0 * 2)) = hv;
            }
        }
        __syncthreads();   // B2: h writes visible

        // R3: W1 GEMM, weights from registers
        f32x4 sacc[4];
        #pragma unroll
        for (int ni = 0; ni < 4; ++ni) sacc[ni] = fz;
        #pragma unroll
        for (int kk = 0; kk < 4; ++kk) {
            int cb = (kk * 32 + lgrp * 8) * 2;
            f16x8 bx[4];
            #pragma unroll
            for (int ni = 0; ni < 4; ++ni)
                bx[ni] = *(const f16x8*)(bufs[cur][0] + swzb(ni * 16 + lrow, cb));
            #pragma unroll
            for (int ni = 0; ni < 4; ++ni)
                sacc[ni] = MFMA16(w1r[kk], bx[ni], sacc[ni]);
        }
        __syncthreads();   // B3: h reads done

        // R4: sk = sacc + b1; rv = sk + affine(raw x).
        // rv16 -> bufs[cur][0]; sk16 -> bufs[cur][1] (in place over raw x bytes).
        {
            float bb[4], sc0[4], sh0[4];
            #pragma unroll
            for (int r = 0; r < 4; ++r) {
                bb[r] = sbias[2][c0 + r];
                sc0[r] = ss[c0 + r];
                sh0[r] = ss[128 + c0 + r];
            }
            #pragma unroll
            for (int ni = 0; ni < 4; ++ni) {
                int tl = ni * 16 + lrow;
                f16x4 xv = *(const f16x4*)(bufs[cur][1] + swzb(tl, c0 * 2));  // RAW
                f16x4 rv16, sk16;
                #pragma unroll
                for (int r = 0; r < 4; ++r) {
                    float sk = sacc[ni][r] + bb[r];
                    sk16[r] = (f16)sk;
                    rv16[r] = (f16)(sk + ((float)xv[r] * sc0[r] + sh0[r]));
                }
                *(f16x4*)(bufs[cur][0] + swzb(tl, c0 * 2)) = rv16;
                *(f16x4*)(bufs[cur][1] + swzb(tl, c0 * 2)) = sk16;
            }
        }
        // loop -> B0
    }

    __syncthreads();
    dense_out2<NTHR>(bufs[(TPB - 1) & 1][0], bufs[(TPB - 1) & 1][1],
                     ro, sb, tb + (TPB - 1) * NT, s1, s2, !last);

    if (!last) flush_statsN<8>(s1, s2, slds, gstats + layer * 256);
}

__global__ __launch_bounds__(L0THR, 4)
void layer0_kernel(const float* __restrict__ x,
                   const float* __restrict__ Wf0, const float* __restrict__ bf0,
                   const float* __restrict__ Wg0, const float* __restrict__ bg0,
                   const f16* __restrict__ w10, const float* __restrict__ b10,
                   f16* __restrict__ rout, f16* __restrict__ ssum,
                   float* __restrict__ gstats)
{
    __shared__ __align__(16) char hbuf[NT * 256];
    __shared__ __align__(16) char w1s[32768];
    __shared__ float wl[6][HD];
    __shared__ float slds0[4][2][HD];
    int tid = threadIdx.x;
    int b = blockIdx.y;
    if (tid < HD) {
        wl[0][tid] = Wf0[tid * 2 + 0]; wl[1][tid] = Wf0[tid * 2 + 1]; wl[2][tid] = bf0[tid];
        wl[3][tid] = Wg0[tid * 2 + 0]; wl[4][tid] = Wg0[tid * 2 + 1]; wl[5][tid] = bg0[tid];
    }
    {
        int cg = tid & 15;
        #pragma unroll
        for (int p = 0; p < 8; ++p) {
            int row = (tid >> 4) + p * 16;
            f16x8 v = *(const f16x8*)(w10 + row * HD + cg * 8);
            *(f16x8*)(w1s + swzb(row, cg * 16)) = v;
        }
    }
    __syncthreads();
    const float* xb = x + (size_t)b * TLEN;
    f16* ro = rout + (size_t)b * TLEN * HD;
    f16* sb = ssum + (size_t)b * OWLEN * HD;
    int cg = tid & 15;
    int lane = tid & 63, w = tid >> 6;
    int m0 = w * 32;
    int lrow = lane & 15, lgrp = lane >> 4;
    const f32x4 fz = {0.f, 0.f, 0.f, 0.f};
    float s1[8] = {}, s2[8] = {};

    for (int ti = 0; ti < TPB; ++ti) {
        int t0 = (blockIdx.x * TPB + ti) * NT;
        if (ti) __syncthreads();
        #pragma unroll
        for (int p = 0; p < NT / 16; ++p) {
            int row = (tid >> 4) + p * 16;
            int gt = t0 + row;
            float xc = xb[gt];
            float xm = (gt >= 1) ? xb[gt - 1] : 0.f;
            f16x8 hv;
            #pragma unroll
            for (int i = 0; i < 8; ++i) {
                int c = cg * 8 + i;
                float fv = wl[0][c] * xm + wl[1][c] * xc + wl[2][c];
                float gv = wl[3][c] * xm + wl[4][c] * xc + wl[5][c];
                hv[i] = (f16)gate_ts(fv, gv);
            }
            *(f16x8*)(hbuf + swzb(row, cg * 16)) = hv;
        }
        __syncthreads();

        f32x4 sacc[2][4];
        #pragma unroll
        for (int mi = 0; mi < 2; ++mi)
            #pragma unroll
            for (int ni = 0; ni < 4; ++ni) sacc[mi][ni] = fz;
        #pragma unroll
        for (int kk = 0; kk < 4; ++kk) {
            int cb = (kk * 32 + lgrp * 8) * 2;
            f16x8 a[2], bx[4];
            #pragma unroll
            for (int mi = 0; mi < 2; ++mi)
                a[mi] = *(const f16x8*)(w1s + swzb(m0 + mi * 16 + lrow, cb));
            #pragma unroll
            for (int ni = 0; ni < 4; ++ni)
                bx[ni] = *(const f16x8*)(hbuf + swzb(ni * 16 + lrow, cb));
            #pragma unroll
            for (int mi = 0; mi < 2; ++mi)
                #pragma unroll
                for (int ni = 0; ni < 4; ++ni)
                    sacc[mi][ni] = MFMA16(a[mi], bx[ni], sacc[mi][ni]);
        }
        __syncthreads();

        #pragma unroll
        for (int mi = 0; mi < 2; ++mi) {
            int c0 = m0 + mi * 16 + lgrp * 4;
            float bb[4];
            #pragma unroll
            for (int r = 0; r < 4; ++r) bb[r] = b10[c0 + r];
            #pragma unroll
            for (int ni = 0; ni < 4; ++ni) {
                int tl = ni * 16 + lrow;
                float xn = xb[t0 + tl];
                f16x4 rv16;
                #pragma unroll
                for (int r = 0; r < 4; ++r)
                    rv16[r] = (f16)(sacc[mi][ni][r] + bb[r] + xn);
                *(f16x4*)(hbuf + swzb(tl, c0 * 2)) = rv16;
            }
        }
        __syncthreads();
        dense_out0<L0THR>(hbuf, xb, ro, sb, t0, s1, s2);
    }
    flush_statsN<4>(s1, s2, slds0, gstats);
}

__global__ __launch_bounds__(HTHR)
void head_gemm(const f16* __restrict__ in, const f16* __restrict__ wm,
               const float* __restrict__ bias, f16* __restrict__ out)
{
    __shared__ __align__(16) char xt[HNT * 256];
    int tid = threadIdx.x;
    int b = blockIdx.y;
    int t0 = blockIdx.x * HNT;
    stage_f16n<HTHR>(in + (size_t)b * OWLEN * HD, t0, OWLEN, xt, HNT);
    __syncthreads();
    int lane = tid & 63, w = tid >> 6;
    int m0 = (w >> 1) * 32, n0 = (w & 1) * 64;
    int lrow = lane & 15, lgrp = lane >> 4;
    const f32x4 fz = {0.f, 0.f, 0.f, 0.f};
    f32x4 acc[2][4];
    #pragma unroll
    for (int mi = 0; mi < 2; ++mi)
        #pragma unroll
        for (int ni = 0; ni < 4; ++ni) acc[mi][ni] = fz;
    #pragma unroll
    for (int kk = 0; kk < 4; ++kk) {
        int kr = kk * 32 + lgrp * 8;
        f16x8 a[2], bx[4];
        #pragma unroll
        for (int mi = 0; mi < 2; ++mi)
            a[mi] = *(const f16x8*)(wm + (m0 + mi * 16 + lrow) * HD + kr);
        #pragma unroll
        for (int ni = 0; ni < 4; ++ni)
            bx[ni] = *(const f16x8*)(xt + swzb(n0 + ni * 16 + lrow, kr * 2));
        #pragma unroll
        for (int mi = 0; mi < 2; ++mi)
            #pragma unroll
            for (int ni = 0; ni < 4; ++ni)
                acc[mi][ni] = MFMA16(a[mi], bx[ni], acc[mi][ni]);
    }
    __syncthreads();   // xt reads done; reuse for relu output
    #pragma unroll
    for (int mi = 0; mi < 2; ++mi) {
        int c0 = m0 + mi * 16 + lgrp * 4;
        float bv[4];
        #pragma unroll
        for (int r = 0; r < 4; ++r) bv[r] = bias[c0 + r];
        #pragma unroll
        for (int ni = 0; ni < 4; ++ni) {
            int tl = n0 + ni * 16 + lrow;
            f16x4 v;
            #pragma unroll
            for (int r = 0; r < 4; ++r) v[r] = (f16)fmaxf(acc[mi][ni][r] + bv[r], 0.f);
            *(f16x4*)(xt + swzb(tl, c0 * 2)) = v;
        }
    }
    __syncthreads();
    f16* ob = out + (size_t)b * OWLEN * HD;
    int cg = tid & 15;
    #pragma unroll
    for (int p = 0; p < HNT / 32; ++p) {
        int row = (tid >> 4) + p * 32;
        int gt = t0 + row;
        if (gt < OWLEN) {
            f16x8 v = *(const f16x8*)(xt + swzb(row, cg * 16));
            *(f16x8*)(ob + (size_t)gt * HD + cg * 8) = v;
        }
    }
}

__global__ __launch_bounds__(HTHR)
void final_kernel(const f16* __restrict__ y2, const f16* __restrict__ whc,
                  const float* __restrict__ bhc, float* __restrict__ out)
{
    __shared__ __align__(16) char yt[130 * 256];
    int tid = threadIdx.x;
    int b = blockIdx.y;
    int t0 = blockIdx.x * HNT;
    stage_f16n<HTHR>(y2 + (size_t)b * OWLEN * HD, t0, OWLEN, yt, 130);
    __syncthreads();
    int lane = tid & 63, w = tid >> 6;
    int tw0 = (w & 1) * 64, o0 = (w >> 1) * 64;
    int lrow = lane & 15, lgrp = lane >> 4;
    const f32x4 fz = {0.f, 0.f, 0.f, 0.f};
    f32x4 acc[4][4];
    #pragma unroll
    for (int ti = 0; ti < 4; ++ti)
        #pragma unroll
        for (int oi = 0; oi < 4; ++oi) acc[ti][oi] = fz;
    #pragma unroll
    for (int tap = 0; tap < 2; ++tap) {
        #pragma unroll
        for (int kk = 0; kk < 4; ++kk) {
            int kr = kk * 32 + lgrp * 8;
            f16x8 a[4], bw[4];
            #pragma unroll
            for (int ti = 0; ti < 4; ++ti) {
                int rrow = tw0 + ti * 16 + lrow + tap;
                a[ti] = *(const f16x8*)(yt + swzb(rrow, kr * 2));
            }
            #pragma unroll
            for (int oi = 0; oi < 4; ++oi) {
                int o = o0 + oi * 16 + lrow;
                bw[oi] = *(const f16x8*)(whc + ((size_t)tap * NCLS2 + o) * HD + kr);
            }
            #pragma unroll
            for (int ti = 0; ti < 4; ++ti)
                #pragma unroll
                for (int oi = 0; oi < 4; ++oi)
                    acc[ti][oi] = MFMA16(a[ti], bw[oi], acc[ti][oi]);
        }
    }
    const int OWM = OWLEN - 1;
    #pragma unroll
    for (int oi = 0; oi < 4; ++oi) {
        int o = o0 + oi * 16 + lrow;
        float bh = bhc[o];
        float* orow = out + ((size_t)b * NCLS2 + o) * OWM;
        #pragma unroll
        for (int ti = 0; ti < 4; ++ti) {
            int tbase = t0 + tw0 + ti * 16 + lgrp * 4;
            if (tbase + 3 < OWM) {
                f32x4u v;
                #pragma unroll
                for (int r = 0; r < 4; ++r) v[r] = acc[ti][oi][r] + bh;
                *(f32x4u*)(orow + tbase) = v;
            } else {
                #pragma unroll
                for (int r = 0; r < 4; ++r) {
                    int t = tbase + r;
                    if (t < OWM) orow[t] = acc[ti][oi][r] + bh;
                }
            }
        }
    }
}

__global__ void conv_fg_kernel(const float* __restrict__ wf, const float* __restrict__ wg,
                               f16* __restrict__ wfh, f16* __restrict__ wgh, int total)
{
    int idx = blockIdx.x * blockDim.x + threadIdx.x;
    if (idx >= total) return;
    int i = idx & 127, o = (idx >> 7) & 127, tap = (idx >> 14) & 1, j = idx >> 15;
    int src = ((j * HD + o) * HD + i) * 2 + tap;
    wfh[idx] = (f16)wf[src];
    wgh[idx] = (f16)wg[src];
}
__global__ void conv_cast_kernel(const float* __restrict__ s, f16* __restrict__ d, int n)
{
    int idx = blockIdx.x * blockDim.x + threadIdx.x;
    if (idx < n) d[idx] = (f16)s[idx];
}
__global__ void conv_whc_kernel(const float* __restrict__ s, f16* __restrict__ d)
{
    int idx = blockIdx.x * blockDim.x + threadIdx.x;
    if (idx >= 2 * NCLS2 * HD) return;
    int c = idx & 127, o = (idx >> 7) & 255, tap = idx >> 15;
    d[idx] = (f16)s[(o * HD + c) * 2 + tap];
}

extern "C" void kernel_launch(void* const* d_in, const int* in_sizes, int n_in,
                              void* d_out, int out_size, void* d_ws, size_t ws_size,
                              hipStream_t stream)
{
    const float* x     = (const float*)d_in[0];
    const float* Wf0   = (const float*)d_in[1];
    const float* bf0   = (const float*)d_in[2];
    const float* Wg0   = (const float*)d_in[3];
    const float* bg0   = (const float*)d_in[4];
    const float* W10   = (const float*)d_in[5];
    const float* b10   = (const float*)d_in[6];
    const float* Wf    = (const float*)d_in[7];
    const float* bf    = (const float*)d_in[8];
    const float* Wg    = (const float*)d_in[9];
    const float* bg    = (const float*)d_in[10];
    const float* W1    = (const float*)d_in[11];
    const float* b1    = (const float*)d_in[12];
    const float* gamma = (const float*)d_in[13];
    const float* beta  = (const float*)d_in[14];
    const float* W11   = (const float*)d_in[15];
    const float* b11   = (const float*)d_in[16];
    const float* W12   = (const float*)d_in[17];
    const float* b12   = (const float*)d_in[18];
    const float* Whc   = (const float*)d_in[19];
    const float* bhc   = (const float*)d_in[20];
    float* out = (float*)d_out;

    const size_t RN  = (size_t)NBATCH * TLEN * HD;    // residual elems (f16)
    const size_t SSN = (size_t)NBATCH * OWLEN * HD;   // skip-sum elems (f16)

    f16* ssum = (f16*)d_ws;
    float* gstats = (float*)(ssum + SSN);
    f16* wfh  = (f16*)(gstats + NLAY * 256);
    f16* wgh  = wfh + 27 * 2 * HD * HD;
    f16* w1h  = wgh + 27 * 2 * HD * HD;
    f16* w10h = w1h + 27 * HD * HD;
    f16* w11h = w10h + HD * HD;
    f16* w12h = w11h + HD * HD;
    f16* whch = w12h + HD * HD;
    f16* rA   = whch + 2 * NCLS2 * HD;
    f16* rB   = rA + RN;

    hipMemsetAsync(gstats, 0, NLAY * 256 * sizeof(float), stream);

    {
        int total = 27 * 2 * HD * HD;
        conv_fg_kernel<<<(total + 255) / 256, 256, 0, stream>>>(Wf, Wg, wfh, wgh, total);
    }
    conv_cast_kernel<<<(27 * HD * HD + 255) / 256, 256, 0, stream>>>(W1, w1h, 27 * HD * HD);
    conv_cast_kernel<<<(HD * HD + 255) / 256, 256, 0, stream>>>(W10, w10h, HD * HD);
    conv_cast_kernel<<<(HD * HD + 255) / 256, 256, 0, stream>>>(W11, w11h, HD * HD);
    conv_cast_kernel<<<(HD * HD + 255) / 256, 256, 0, stream>>>(W12, w12h, HD * HD);
    conv_whc_kernel<<<(2 * NCLS2 * HD + 255) / 256, 256, 0, stream>>>(Whc, whch);

    dim3 lgrid(TLEN / (NT * TPB), NBATCH);   // 128 x 4 = 512 blocks
    layer0_kernel<<<lgrid, L0THR, 0, stream>>>(x, Wf0, bf0, Wg0, bg0, w10h, b10, rA, ssum, gstats);

    f16* rbufs[2] = {rA, rB};
    for (int l = 1; l < NLAY; ++l) {
        int j = l - 1;
        int dil = 1 << (l % 14);
        layer_kernel<<<lgrid, NTHR, 0, stream>>>(
            rbufs[(l - 1) & 1], rbufs[l & 1], ssum, gstats,
            wfh + (size_t)j * 2 * HD * HD, wgh + (size_t)j * 2 * HD * HD,
            w1h + (size_t)j * HD * HD,
            bf + (size_t)j * HD, bg + (size_t)j * HD, b1 + (size_t)j * HD,
            gamma + (size_t)(l - 1) * HD, beta + (size_t)(l - 1) * HD, l, dil,
            (l == NLAY - 1) ? 1 : 0);
    }

    dim3 hgrid((OWLEN + HNT - 1) / HNT, NBATCH);
    head_gemm<<<hgrid, HTHR, 0, stream>>>(ssum, w11h, b11, rA);
    head_gemm<<<hgrid, HTHR, 0, stream>>>(rA, w12h, b12, rB);
    final_kernel<<<hgrid, HTHR, 0, stream>>>(rB, whch, bhc, out);
}

// Round 17
// 1866.108 us; speedup vs baseline: 1.1335x; 1.0328x over previous
//
#include <hip/hip_runtime.h>
#include <hip/hip_fp16.h>

#define HD 128
#define TLEN 49152
#define NBATCH 4
#define NCLS2 256
#define OWLEN 16386
#define SKIP0 (TLEN - OWLEN)
#define NLAY 28
#define NT 64          // time rows per tile
#define TPB 6          // tiles per block -> grid.x = 128
#define NTHR 512       // 8 waves, each owns 16 output channels
#define L0THR 256      // layer0 stays 4-wave
#define HNT 128        // head tile
#define HTHR 512

typedef _Float16 f16;
typedef _Float16 f16x8 __attribute__((ext_vector_type(8)));
typedef _Float16 f16x4 __attribute__((ext_vector_type(4)));
typedef float f32x4 __attribute__((ext_vector_type(4)));
typedef float f32x4u __attribute__((ext_vector_type(4), aligned(4)));

#define MFMA16(a, b, c) __builtin_amdgcn_mfma_f32_16x16x32_f16(a, b, c, 0, 0, 0)

// fused tanh(f)*sigmoid(g) = sign(f)*(1-u)*rcp((1+u)*(1+v)), u=e^{-2|f|}, v=e^{-g}
__device__ __forceinline__ float gate_ts(float fv, float gv) {
    float u = __expf(-2.f * fabsf(fv));
    float v = __expf(-gv);
    float num = copysignf(1.f - u, fv);
    return num * __builtin_amdgcn_rcpf((1.f + u) * (1.f + v));
}

// swizzled LDS byte offset for a [rows][128ch] f16 tile (row stride 256B).
// FULL 4-bit slot XOR: 16 lanes sweeping 16 rows at one col-slot hit all 16
// 16B slots -> 2-way max (free). The old (row&7) 3-bit XOR left ~4-way
// conflicts on ds_read_b128 (R16 PMC: 6.39M conflict-cycles/dispatch = 14%).
__device__ __forceinline__ int swzb(int row, int cb) { return row * 256 + (cb ^ ((row & 15) << 4)); }

// async global->LDS, 16B/lane. LDS dest linear; swizzle via pre-swizzled per-lane
// GLOBAL source address.
__device__ __forceinline__ void gld_lds16(const void* g, void* l) {
    __builtin_amdgcn_global_load_lds((const __attribute__((address_space(1))) void*)g,
                                     (__attribute__((address_space(3))) void*)l, 16, 0, 0);
}

// wave w stages rows [w*8, w*8+8) of a 64x128 f16 tile (two 1KB issues)
__device__ __forceinline__ void stage_async(const f16* __restrict__ rb, int tbase,
                                            char* buf, int w, int lane)
{
    int rgrp = lane >> 4;
    int cb = (lane & 15) * 16;
    #pragma unroll
    for (int q = 0; q < 2; ++q) {
        int row0 = w * 8 + q * 4;
        int r = row0 + rgrp;
        int gt = tbase + r;
        const char* src = (const char*)(rb + (size_t)gt * HD) + (cb ^ ((r & 15) << 4));
        gld_lds16(src, buf + row0 * 256);
    }
}

template <int NTH>
__device__ __forceinline__ void stage_f16n(const f16* __restrict__ src, int tbase, int tlim,
                                           char* dst, int nrows)
{
    int tid = threadIdx.x;
    int cg = tid & 15;
    for (int row = tid >> 4; row < nrows; row += NTH / 16) {
        int gt = tbase + row;
        f16x8 v;
        if (gt >= 0 && gt < tlim) {
            v = *(const f16x8*)(src + (size_t)gt * HD + cg * 8);
        } else {
            #pragma unroll
            for (int i = 0; i < 8; ++i) v[i] = (f16)0.f;
        }
        *(f16x8*)(dst + swzb(row, cg * 16)) = v;
    }
}

// dense output pass for layer kernels: rvbuf holds rv16, skbuf holds sk16.
// ssum RMW as packed f16 vector add (v_pk_add_f16; numerically identical to
// f32-add-then-round since two f16 summands are exact in f32).
template <int NTH>
__device__ __forceinline__ void dense_out2(const char* rvbuf, const char* skbuf,
                                           f16* __restrict__ ro, f16* __restrict__ sb,
                                           int t0, float* s1, float* s2, int wout)
{
    int tid = threadIdx.x;
    int cg = tid & 15;
    #pragma unroll
    for (int p = 0; p < NT / (NTH / 16); ++p) {
        int row = (tid >> 4) + p * (NTH / 16);
        int gt = t0 + row;
        f16x8 rv = *(const f16x8*)(rvbuf + swzb(row, cg * 16));
        if (wout) *(f16x8*)(ro + (size_t)gt * HD + cg * 8) = rv;
        float rvf[8];
        #pragma unroll
        for (int i = 0; i < 8; ++i) {
            rvf[i] = (float)rv[i];
            s1[i] += rvf[i];
            s2[i] += rvf[i] * rvf[i];
        }
        if (gt >= SKIP0) {
            f16x8 sk = *(const f16x8*)(skbuf + swzb(row, cg * 16));
            f16* sp = sb + (size_t)(gt - SKIP0) * HD + cg * 8;
            f16x8 s0 = *(const f16x8*)sp;
            s0 = s0 + sk;   // packed f16 adds
            *(f16x8*)sp = s0;
        }
    }
}

// layer0 dense pass (skip = rv - x broadcast; ssum WRITE, f16)
template <int NTH>
__device__ __forceinline__ void dense_out0(const char* rvbuf, const float* __restrict__ xraw,
                                           f16* __restrict__ ro, f16* __restrict__ sb,
                                           int t0, float* s1, float* s2)
{
    int tid = threadIdx.x;
    int cg = tid & 15;
    #pragma unroll
    for (int p = 0; p < NT / (NTH / 16); ++p) {
        int row = (tid >> 4) + p * (NTH / 16);
        int gt = t0 + row;
        f16x8 rv = *(const f16x8*)(rvbuf + swzb(row, cg * 16));
        *(f16x8*)(ro + (size_t)gt * HD + cg * 8) = rv;
        float rvf[8];
        #pragma unroll
        for (int i = 0; i < 8; ++i) {
            rvf[i] = (float)rv[i];
            s1[i] += rvf[i];
            s2[i] += rvf[i] * rvf[i];
        }
        if (gt >= SKIP0) {
            float xv = xraw[gt];
            f16* sp = sb + (size_t)(gt - SKIP0) * HD + cg * 8;
            f16x8 s0;
            #pragma unroll
            for (int i = 0; i < 8; ++i) s0[i] = (f16)(rvf[i] - xv);
            *(f16x8*)sp = s0;
        }
    }
}

// cross-wave stats flush; NW = waves per block
template <int NW>
__device__ __forceinline__ void flush_statsN(float* s1, float* s2,
                                             float (*slds)[2][HD], float* __restrict__ gs)
{
    int tid = threadIdx.x;
    int lane = tid & 63, w = tid >> 6;
    #pragma unroll
    for (int i = 0; i < 8; ++i) {
        s1[i] += __shfl_xor(s1[i], 16); s1[i] += __shfl_xor(s1[i], 32);
        s2[i] += __shfl_xor(s2[i], 16); s2[i] += __shfl_xor(s2[i], 32);
    }
    if (lane < 16) {
        #pragma unroll
        for (int i = 0; i < 8; ++i) {
            slds[w][0][lane * 8 + i] = s1[i];
            slds[w][1][lane * 8 + i] = s2[i];
        }
    }
    __syncthreads();
    if (tid < HD) {
        float a = 0.f;
        #pragma unroll
        for (int k = 0; k < NW; ++k) a += slds[k][0][tid];
        atomicAdd(&gs[tid], a);
    } else if (tid < 2 * HD) {
        int c = tid - HD;
        float a = 0.f;
        #pragma unroll
        for (int k = 0; k < NW; ++k) a += slds[k][1][c];
        atomicAdd(&gs[HD + c], a);
    }
}

__global__ __launch_bounds__(NTHR, 2)
void layer_kernel(const f16* __restrict__ rin, f16* __restrict__ rout,
                  f16* __restrict__ ssum, float* __restrict__ gstats,
                  const f16* __restrict__ wf, const f16* __restrict__ wg,
                  const f16* __restrict__ w1,
                  const float* __restrict__ bf, const float* __restrict__ bg,
                  const float* __restrict__ b1,
                  const float* __restrict__ gamma, const float* __restrict__ beta,
                  int layer, int dil, int last)
{
    __shared__ __align__(16) char bufs[2][2][NT * 256];  // [parity][tap] 64 KB
    __shared__ float ss[256];
    __shared__ float sbias[3][HD];
    __shared__ float slds[8][2][HD];

    int tid = threadIdx.x;
    int b = blockIdx.y;

    if (tid < HD) {
        float n = (float)(NBATCH * TLEN);
        float s = gstats[(layer - 1) * 256 + tid];
        float q = gstats[(layer - 1) * 256 + 128 + tid];
        float mean = s / n;
        float var = q / n - mean * mean;
        float sc = gamma[tid] * rsqrtf(var + 1e-5f);
        ss[tid] = sc;
        ss[128 + tid] = beta[tid] - mean * sc;
        sbias[0][tid] = bf[tid];
        sbias[1][tid] = bg[tid];
        sbias[2][tid] = b1[tid];
    }
    __syncthreads();   // ss ready for weight fold

    int lane = tid & 63, w = tid >> 6;
    int m0 = w * 16;
    int lrow = lane & 15, lgrp = lane >> 4;
    const f32x4 fz = {0.f, 0.f, 0.f, 0.f};

    // load conv weights, fold BN scale into them, accumulate shift->bias corr
    f16x8 wfr[2][4], wgr[2][4], w1r[4];
    float corrF = 0.f, corrG = 0.f;
    #pragma unroll
    for (int kk = 0; kk < 4; ++kk) {
        int ck = kk * 32 + lgrp * 8;
        float scv[8], shv[8];
        #pragma unroll
        for (int i = 0; i < 8; ++i) { scv[i] = ss[ck + i]; shv[i] = ss[128 + ck + i]; }
        #pragma unroll
        for (int tap = 0; tap < 2; ++tap) {
            int o = (m0 + lrow) * HD + ck;
            f16x8 vF = *(const f16x8*)(wf + tap * HD * HD + o);
            f16x8 vG = *(const f16x8*)(wg + tap * HD * HD + o);
            #pragma unroll
            for (int i = 0; i < 8; ++i) {
                corrF += (float)vF[i] * shv[i];
                corrG += (float)vG[i] * shv[i];
                vF[i] = (f16)((float)vF[i] * scv[i]);
                vG[i] = (f16)((float)vG[i] * scv[i]);
            }
            wfr[tap][kk] = vF;
            wgr[tap][kk] = vG;
        }
        w1r[kk] = *(const f16x8*)(w1 + (m0 + lrow) * HD + ck);
    }
    corrF += __shfl_xor(corrF, 16); corrF += __shfl_xor(corrF, 32);
    corrG += __shfl_xor(corrG, 16); corrG += __shfl_xor(corrG, 32);
    if (lane < 16) {
        sbias[0][m0 + lane] += corrF;
        sbias[1][m0 + lane] += corrG;
    }

    const f16* rb = rin + (size_t)b * TLEN * HD;
    f16* ro = rout + (size_t)b * TLEN * HD;
    f16* sb = ssum + (size_t)b * OWLEN * HD;

    float s1[8] = {}, s2[8] = {};
    int tb = blockIdx.x * TPB * NT;
    int c0 = m0 + lgrp * 4;
    int cg = tid & 15;

    // per-thread causal pad value (raw value whose normalized form is 0)
    float padv[8];
    #pragma unroll
    for (int i = 0; i < 8; ++i)
        padv[i] = -ss[128 + cg * 8 + i] * __builtin_amdgcn_rcpf(ss[cg * 8 + i]);

    // prologue: issue tile-0 stage (raw)
    stage_async(rb, tb, bufs[0][1], w, lane);
    stage_async(rb, tb - dil, bufs[0][0], w, lane);

    for (int ti = 0; ti < TPB; ++ti) {
        int t0 = tb + ti * NT;
        int cur = ti & 1;
        int prv = cur ^ 1;
        __syncthreads();   // B0: staged tiles landed + rv/sk writes(ti-1) visible

        // causal boundary patch: padded positions get padv (normalized -> 0)
        if (t0 < dil) {
            for (int r0 = tid >> 4; r0 < NT; r0 += NTHR / 16) {
                if (t0 - dil + r0 < 0) {
                    f16x8 v;
                    #pragma unroll
                    for (int i = 0; i < 8; ++i) v[i] = (f16)padv[i];
                    *(f16x8*)(bufs[cur][0] + swzb(r0, cg * 16)) = v;
                }
            }
            __syncthreads();
        }

        // R1: dense_out(t-1) [parity prv] ∥ fg GEMM(t) [parity cur]
        if (ti > 0)
            dense_out2<NTHR>(bufs[prv][0], bufs[prv][1], ro, sb, t0 - NT, s1, s2, !last);

        f32x4 facc[4], gacc[4];
        #pragma unroll
        for (int ni = 0; ni < 4; ++ni) { facc[ni] = fz; gacc[ni] = fz; }
        #pragma unroll
        for (int tap = 0; tap < 2; ++tap) {
            const char* xt = bufs[cur][tap];
            #pragma unroll
            for (int kk = 0; kk < 4; ++kk) {
                f16x8 bx[4];
                #pragma unroll
                for (int ni = 0; ni < 4; ++ni)
                    bx[ni] = *(const f16x8*)(xt + swzb(ni * 16 + lrow, (kk * 32 + lgrp * 8) * 2));
                #pragma unroll
                for (int ni = 0; ni < 4; ++ni) {
                    facc[ni] = MFMA16(wfr[tap][kk], bx[ni], facc[ni]);
                    gacc[ni] = MFMA16(wgr[tap][kk], bx[ni], gacc[ni]);
                }
            }
        }
        __syncthreads();   // B1: tap reads + dense's prv LDS reads done

        // R2: issue stage(t+1) into prv parity; gate-write h into bufs[cur][0]
        if (ti + 1 < TPB) {
            stage_async(rb, t0 + NT, bufs[prv][1], w, lane);
            stage_async(rb, t0 + NT - dil, bufs[prv][0], w, lane);
        }
        {
            float bfv[4], bgv[4];
            #pragma unroll
            for (int r = 0; r < 4; ++r) { bfv[r] = sbias[0][c0 + r]; bgv[r] = sbias[1][c0 + r]; }
            #pragma unroll
            for (int ni = 0; ni < 4; ++ni) {
                int t = ni * 16 + lrow;
                f16x4 hv;
                #pragma unroll
                for (int r = 0; r < 4; ++r)
                    hv[r] = (f16)gate_ts(facc[ni][r] + bfv[r], gacc[ni][r] + bgv[r]);
                *(f16x4*)(bufs[cur][0] + swzb(t, c0 * 2)) = hv;
            }
        }
        __syncthreads();   // B2: h writes visible

        // R3: W1 GEMM, weights from registers
        f32x4 sacc[4];
        #pragma unroll
        for (int ni = 0; ni < 4; ++ni) sacc[ni] = fz;
        #pragma unroll
        for (int kk = 0; kk < 4; ++kk) {
            int cb = (kk * 32 + lgrp * 8) * 2;
            f16x8 bx[4];
            #pragma unroll
            for (int ni = 0; ni < 4; ++ni)
                bx[ni] = *(const f16x8*)(bufs[cur][0] + swzb(ni * 16 + lrow, cb));
            #pragma unroll
            for (int ni = 0; ni < 4; ++ni)
                sacc[ni] = MFMA16(w1r[kk], bx[ni], sacc[ni]);
        }
        __syncthreads();   // B3: h reads done

        // R4: sk = sacc + b1; rv = sk + affine(raw x).
        // rv16 -> bufs[cur][0]; sk16 -> bufs[cur][1] (in place over raw x bytes).
        {
            float bb[4], sc0[4], sh0[4];
            #pragma unroll
            for (int r = 0; r < 4; ++r) {
                bb[r] = sbias[2][c0 + r];
                sc0[r] = ss[c0 + r];
                sh0[r] = ss[128 + c0 + r];
            }
            #pragma unroll
            for (int ni = 0; ni < 4; ++ni) {
                int tl = ni * 16 + lrow;
                f16x4 xv = *(const f16x4*)(bufs[cur][1] + swzb(tl, c0 * 2));  // RAW
                f16x4 rv16, sk16;
                #pragma unroll
                for (int r = 0; r < 4; ++r) {
                    float sk = sacc[ni][r] + bb[r];
                    sk16[r] = (f16)sk;
                    rv16[r] = (f16)(sk + ((float)xv[r] * sc0[r] + sh0[r]));
                }
                *(f16x4*)(bufs[cur][0] + swzb(tl, c0 * 2)) = rv16;
                *(f16x4*)(bufs[cur][1] + swzb(tl, c0 * 2)) = sk16;
            }
        }
        // loop -> B0
    }

    __syncthreads();
    dense_out2<NTHR>(bufs[(TPB - 1) & 1][0], bufs[(TPB - 1) & 1][1],
                     ro, sb, tb + (TPB - 1) * NT, s1, s2, !last);

    if (!last) flush_statsN<8>(s1, s2, slds, gstats + layer * 256);
}

__global__ __launch_bounds__(L0THR, 4)
void layer0_kernel(const float* __restrict__ x,
                   const float* __restrict__ Wf0, const float* __restrict__ bf0,
                   const float* __restrict__ Wg0, const float* __restrict__ bg0,
                   const f16* __restrict__ w10, const float* __restrict__ b10,
                   f16* __restrict__ rout, f16* __restrict__ ssum,
                   float* __restrict__ gstats)
{
    __shared__ __align__(16) char hbuf[NT * 256];
    __shared__ __align__(16) char w1s[32768];
    __shared__ float wl[6][HD];
    __shared__ float slds0[4][2][HD];
    int tid = threadIdx.x;
    int b = blockIdx.y;
    if (tid < HD) {
        wl[0][tid] = Wf0[tid * 2 + 0]; wl[1][tid] = Wf0[tid * 2 + 1]; wl[2][tid] = bf0[tid];
        wl[3][tid] = Wg0[tid * 2 + 0]; wl[4][tid] = Wg0[tid * 2 + 1]; wl[5][tid] = bg0[tid];
    }
    {
        int cg = tid & 15;
        #pragma unroll
        for (int p = 0; p < 8; ++p) {
            int row = (tid >> 4) + p * 16;
            f16x8 v = *(const f16x8*)(w10 + row * HD + cg * 8);
            *(f16x8*)(w1s + swzb(row, cg * 16)) = v;
        }
    }
    __syncthreads();
    const float* xb = x + (size_t)b * TLEN;
    f16* ro = rout + (size_t)b * TLEN * HD;
    f16* sb = ssum + (size_t)b * OWLEN * HD;
    int cg = tid & 15;
    int lane = tid & 63, w = tid >> 6;
    int m0 = w * 32;
    int lrow = lane & 15, lgrp = lane >> 4;
    const f32x4 fz = {0.f, 0.f, 0.f, 0.f};
    float s1[8] = {}, s2[8] = {};

    for (int ti = 0; ti < TPB; ++ti) {
        int t0 = (blockIdx.x * TPB + ti) * NT;
        if (ti) __syncthreads();
        #pragma unroll
        for (int p = 0; p < NT / 16; ++p) {
            int row = (tid >> 4) + p * 16;
            int gt = t0 + row;
            float xc = xb[gt];
            float xm = (gt >= 1) ? xb[gt - 1] : 0.f;
            f16x8 hv;
            #pragma unroll
            for (int i = 0; i < 8; ++i) {
                int c = cg * 8 + i;
                float fv = wl[0][c] * xm + wl[1][c] * xc + wl[2][c];
                float gv = wl[3][c] * xm + wl[4][c] * xc + wl[5][c];
                hv[i] = (f16)gate_ts(fv, gv);
            }
            *(f16x8*)(hbuf + swzb(row, cg * 16)) = hv;
        }
        __syncthreads();

        f32x4 sacc[2][4];
        #pragma unroll
        for (int mi = 0; mi < 2; ++mi)
            #pragma unroll
            for (int ni = 0; ni < 4; ++ni) sacc[mi][ni] = fz;
        #pragma unroll
        for (int kk = 0; kk < 4; ++kk) {
            int cb = (kk * 32 + lgrp * 8) * 2;
            f16x8 a[2], bx[4];
            #pragma unroll
            for (int mi = 0; mi < 2; ++mi)
                a[mi] = *(const f16x8*)(w1s + swzb(m0 + mi * 16 + lrow, cb));
            #pragma unroll
            for (int ni = 0; ni < 4; ++ni)
                bx[ni] = *(const f16x8*)(hbuf + swzb(ni * 16 + lrow, cb));
            #pragma unroll
            for (int mi = 0; mi < 2; ++mi)
                #pragma unroll
                for (int ni = 0; ni < 4; ++ni)
                    sacc[mi][ni] = MFMA16(a[mi], bx[ni], sacc[mi][ni]);
        }
        __syncthreads();

        #pragma unroll
        for (int mi = 0; mi < 2; ++mi) {
            int c0 = m0 + mi * 16 + lgrp * 4;
            float bb[4];
            #pragma unroll
            for (int r = 0; r < 4; ++r) bb[r] = b10[c0 + r];
            #pragma unroll
            for (int ni = 0; ni < 4; ++ni) {
                int tl = ni * 16 + lrow;
                float xn = xb[t0 + tl];
                f16x4 rv16;
                #pragma unroll
                for (int r = 0; r < 4; ++r)
                    rv16[r] = (f16)(sacc[mi][ni][r] + bb[r] + xn);
                *(f16x4*)(hbuf + swzb(tl, c0 * 2)) = rv16;
            }
        }
        __syncthreads();
        dense_out0<L0THR>(hbuf, xb, ro, sb, t0, s1, s2);
    }
    flush_statsN<4>(s1, s2, slds0, gstats);
}

__global__ __launch_bounds__(HTHR)
void head_gemm(const f16* __restrict__ in, const f16* __restrict__ wm,
               const float* __restrict__ bias, f16* __restrict__ out)
{
    __shared__ __align__(16) char xt[HNT * 256];
    int tid = threadIdx.x;
    int b = blockIdx.y;
    int t0 = blockIdx.x * HNT;
    stage_f16n<HTHR>(in + (size_t)b * OWLEN * HD, t0, OWLEN, xt, HNT);
    __syncthreads();
    int lane = tid & 63, w = tid >> 6;
    int m0 = (w >> 1) * 32, n0 = (w & 1) * 64;
    int lrow = lane & 15, lgrp = lane >> 4;
    const f32x4 fz = {0.f, 0.f, 0.f, 0.f};
    f32x4 acc[2][4];
    #pragma unroll
    for (int mi = 0; mi < 2; ++mi)
        #pragma unroll
        for (int ni = 0; ni < 4; ++ni) acc[mi][ni] = fz;
    #pragma unroll
    for (int kk = 0; kk < 4; ++kk) {
        int kr = kk * 32 + lgrp * 8;
        f16x8 a[2], bx[4];
        #pragma unroll
        for (int mi = 0; mi < 2; ++mi)
            a[mi] = *(const f16x8*)(wm + (m0 + mi * 16 + lrow) * HD + kr);
        #pragma unroll
        for (int ni = 0; ni < 4; ++ni)
            bx[ni] = *(const f16x8*)(xt + swzb(n0 + ni * 16 + lrow, kr * 2));
        #pragma unroll
        for (int mi = 0; mi < 2; ++mi)
            #pragma unroll
            for (int ni = 0; ni < 4; ++ni)
                acc[mi][ni] = MFMA16(a[mi], bx[ni], acc[mi][ni]);
    }
    __syncthreads();   // xt reads done; reuse for relu output
    #pragma unroll
    for (int mi = 0; mi < 2; ++mi) {
        int c0 = m0 + mi * 16 + lgrp * 4;
        float bv[4];
        #pragma unroll
        for (int r = 0; r < 4; ++r) bv[r] = bias[c0 + r];
        #pragma unroll
        for (int ni = 0; ni < 4; ++ni) {
            int tl = n0 + ni * 16 + lrow;
            f16x4 v;
            #pragma unroll
            for (int r = 0; r < 4; ++r) v[r] = (f16)fmaxf(acc[mi][ni][r] + bv[r], 0.f);
            *(f16x4*)(xt + swzb(tl, c0 * 2)) = v;
        }
    }
    __syncthreads();
    f16* ob = out + (size_t)b * OWLEN * HD;
    int cg = tid & 15;
    #pragma unroll
    for (int p = 0; p < HNT / 32; ++p) {
        int row = (tid >> 4) + p * 32;
        int gt = t0 + row;
        if (gt < OWLEN) {
            f16x8 v = *(const f16x8*)(xt + swzb(row, cg * 16));
            *(f16x8*)(ob + (size_t)gt * HD + cg * 8) = v;
        }
    }
}

__global__ __launch_bounds__(HTHR)
void final_kernel(const f16* __restrict__ y2, const f16* __restrict__ whc,
                  const float* __restrict__ bhc, float* __restrict__ out)
{
    __shared__ __align__(16) char yt[130 * 256];
    int tid = threadIdx.x;
    int b = blockIdx.y;
    int t0 = blockIdx.x * HNT;
    stage_f16n<HTHR>(y2 + (size_t)b * OWLEN * HD, t0, OWLEN, yt, 130);
    __syncthreads();
    int lane = tid & 63, w = tid >> 6;
    int tw0 = (w & 1) * 64, o0 = (w >> 1) * 64;
    int lrow = lane & 15, lgrp = lane >> 4;
    const f32x4 fz = {0.f, 0.f, 0.f, 0.f};
    f32x4 acc[4][4];
    #pragma unroll
    for (int ti = 0; ti < 4; ++ti)
        #pragma unroll
        for (int oi = 0; oi < 4; ++oi) acc[ti][oi] = fz;
    #pragma unroll
    for (int tap = 0; tap < 2; ++tap) {
        #pragma unroll
        for (int kk = 0; kk < 4; ++kk) {
            int kr = kk * 32 + lgrp * 8;
            f16x8 a[4], bw[4];
            #pragma unroll
            for (int ti = 0; ti < 4; ++ti) {
                int rrow = tw0 + ti * 16 + lrow + tap;
                a[ti] = *(const f16x8*)(yt + swzb(rrow, kr * 2));
            }
            #pragma unroll
            for (int oi = 0; oi < 4; ++oi) {
                int o = o0 + oi * 16 + lrow;
                bw[oi] = *(const f16x8*)(whc + ((size_t)tap * NCLS2 + o) * HD + kr);
            }
            #pragma unroll
            for (int ti = 0; ti < 4; ++ti)
                #pragma unroll
                for (int oi = 0; oi < 4; ++oi)
                    acc[ti][oi] = MFMA16(a[ti], bw[oi], acc[ti][oi]);
        }
    }
    const int OWM = OWLEN - 1;
    #pragma unroll
    for (int oi = 0; oi < 4; ++oi) {
        int o = o0 + oi * 16 + lrow;
        float bh = bhc[o];
        float* orow = out + ((size_t)b * NCLS2 + o) * OWM;
        #pragma unroll
        for (int ti = 0; ti < 4; ++ti) {
            int tbase = t0 + tw0 + ti * 16 + lgrp * 4;
            if (tbase + 3 < OWM) {
                f32x4u v;
                #pragma unroll
                for (int r = 0; r < 4; ++r) v[r] = acc[ti][oi][r] + bh;
                *(f32x4u*)(orow + tbase) = v;
            } else {
                #pragma unroll
                for (int r = 0; r < 4; ++r) {
                    int t = tbase + r;
                    if (t < OWM) orow[t] = acc[ti][oi][r] + bh;
                }
            }
        }
    }
}

__global__ void conv_fg_kernel(const float* __restrict__ wf, const float* __restrict__ wg,
                               f16* __restrict__ wfh, f16* __restrict__ wgh, int total)
{
    int idx = blockIdx.x * blockDim.x + threadIdx.x;
    if (idx >= total) return;
    int i = idx & 127, o = (idx >> 7) & 127, tap = (idx >> 14) & 1, j = idx >> 15;
    int src = ((j * HD + o) * HD + i) * 2 + tap;
    wfh[idx] = (f16)wf[src];
    wgh[idx] = (f16)wg[src];
}
__global__ void conv_cast_kernel(const float* __restrict__ s, f16* __restrict__ d, int n)
{
    int idx = blockIdx.x * blockDim.x + threadIdx.x;
    if (idx < n) d[idx] = (f16)s[idx];
}
__global__ void conv_whc_kernel(const float* __restrict__ s, f16* __restrict__ d)
{
    int idx = blockIdx.x * blockDim.x + threadIdx.x;
    if (idx >= 2 * NCLS2 * HD) return;
    int c = idx & 127, o = (idx >> 7) & 255, tap = idx >> 15;
    d[idx] = (f16)s[(o * HD + c) * 2 + tap];
}

extern "C" void kernel_launch(void* const* d_in, const int* in_sizes, int n_in,
                              void* d_out, int out_size, void* d_ws, size_t ws_size,
                              hipStream_t stream)
{
    const float* x     = (const float*)d_in[0];
    const float* Wf0   = (const float*)d_in[1];
    const float* bf0   = (const float*)d_in[2];
    const float* Wg0   = (const float*)d_in[3];
    const float* bg0   = (const float*)d_in[4];
    const float* W10   = (const float*)d_in[5];
    const float* b10   = (const float*)d_in[6];
    const float* Wf    = (const float*)d_in[7];
    const float* bf    = (const float*)d_in[8];
    const float* Wg    = (const float*)d_in[9];
    const float* bg    = (const float*)d_in[10];
    const float* W1    = (const float*)d_in[11];
    const float* b1    = (const float*)d_in[12];
    const float* gamma = (const float*)d_in[13];
    const float* beta  = (const float*)d_in[14];
    const float* W11   = (const float*)d_in[15];
    const float* b11   = (const float*)d_in[16];
    const float* W12   = (const float*)d_in[17];
    const float* b12   = (const float*)d_in[18];
    const float* Whc   = (const float*)d_in[19];
    const float* bhc   = (const float*)d_in[20];
    float* out = (float*)d_out;

    const size_t RN  = (size_t)NBATCH * TLEN * HD;    // residual elems (f16)
    const size_t SSN = (size_t)NBATCH * OWLEN * HD;   // skip-sum elems (f16)

    f16* ssum = (f16*)d_ws;
    float* gstats = (float*)(ssum + SSN);
    f16* wfh  = (f16*)(gstats + NLAY * 256);
    f16* wgh  = wfh + 27 * 2 * HD * HD;
    f16* w1h  = wgh + 27 * 2 * HD * HD;
    f16* w10h = w1h + 27 * HD * HD;
    f16* w11h = w10h + HD * HD;
    f16* w12h = w11h + HD * HD;
    f16* whch = w12h + HD * HD;
    f16* rA   = whch + 2 * NCLS2 * HD;
    f16* rB   = rA + RN;

    hipMemsetAsync(gstats, 0, NLAY * 256 * sizeof(float), stream);

    {
        int total = 27 * 2 * HD * HD;
        conv_fg_kernel<<<(total + 255) / 256, 256, 0, stream>>>(Wf, Wg, wfh, wgh, total);
    }
    conv_cast_kernel<<<(27 * HD * HD + 255) / 256, 256, 0, stream>>>(W1, w1h, 27 * HD * HD);
    conv_cast_kernel<<<(HD * HD + 255) / 256, 256, 0, stream>>>(W10, w10h, HD * HD);
    conv_cast_kernel<<<(HD * HD + 255) / 256, 256, 0, stream>>>(W11, w11h, HD * HD);
    conv_cast_kernel<<<(HD * HD + 255) / 256, 256, 0, stream>>>(W12, w12h, HD * HD);
    conv_whc_kernel<<<(2 * NCLS2 * HD + 255) / 256, 256, 0, stream>>>(Whc, whch);

    dim3 lgrid(TLEN / (NT * TPB), NBATCH);   // 128 x 4 = 512 blocks
    layer0_kernel<<<lgrid, L0THR, 0, stream>>>(x, Wf0, bf0, Wg0, bg0, w10h, b10, rA, ssum, gstats);

    f16* rbufs[2] = {rA, rB};
    for (int l = 1; l < NLAY; ++l) {
        int j = l - 1;
        int dil = 1 << (l % 14);
        layer_kernel<<<lgrid, NTHR, 0, stream>>>(
            rbufs[(l - 1) & 1], rbufs[l & 1], ssum, gstats,
            wfh + (size_t)j * 2 * HD * HD, wgh + (size_t)j * 2 * HD * HD,
            w1h + (size_t)j * HD * HD,
            bf + (size_t)j * HD, bg + (size_t)j * HD, b1 + (size_t)j * HD,
            gamma + (size_t)(l - 1) * HD, beta + (size_t)(l - 1) * HD, l, dil,
            (l == NLAY - 1) ? 1 : 0);
    }

    dim3 hgrid((OWLEN + HNT - 1) / HNT, NBATCH);
    head_gemm<<<hgrid, HTHR, 0, stream>>>(ssum, w11h, b11, rA);
    head_gemm<<<hgrid, HTHR, 0, stream>>>(rA, w12h, b12, rB);
    final_kernel<<<hgrid, HTHR, 0, stream>>>(rB, whch, bhc, out);
}